// Round 1
// baseline (268.031 us; speedup 1.0000x reference)
//
#include <hip/hip_runtime.h>
#include <math.h>

// ---------------- constants ----------------
#define Bsz   8
#define CHUNK 16
#define D     256      // d_model = num_heads = num_patches = 256
#define S     257      // seq len
#define MLP   1024
#define NCLS  1000
#define M_ROWS (Bsz * S)   // 2056

__device__ __forceinline__ float wave_sum(float v) {
  #pragma unroll
  for (int m = 1; m < 64; m <<= 1) v += __shfl_xor(v, m, 64);
  return v;
}

// ---------------- cls row: t[b,0,:] = class_token + pos_emb[0] ----------------
__global__ __launch_bounds__(256) void cls_kernel(const float* __restrict__ ct,
                                                  const float* __restrict__ pos,
                                                  float* __restrict__ t) {
  int b = blockIdx.x, d = threadIdx.x;
  t[((size_t)b * S) * D + d] = ct[d] + pos[d];
}

// ---------------- patch embed ----------------
// t[b, 1+h, n] = sum_i p[b,n,i]*patch_w[h,n,i] + patch_b[h,n] + pos_emb[1+h,n]
// grid: 1024 blocks = (hquad 0..3) * 256 n-blocks; 256 threads (4 waves)
__global__ __launch_bounds__(256) void patch_kernel(const float* __restrict__ x,
                                                    const float* __restrict__ pw,
                                                    const float* __restrict__ pb,
                                                    const float* __restrict__ pos,
                                                    float* __restrict__ t) {
  int n  = blockIdx.x & 255;
  int hb = (blockIdx.x >> 8) * 64;     // h range [hb, hb+64)
  int pi = n >> 4, pj = n & 15;
  int lane = threadIdx.x & 63, w = threadIdx.x >> 6;
  // lane's chunk of i: i = lane*4 .. lane*4+3  ->  r = lane>>2, c0 = (lane&3)*4
  int r = lane >> 2, c0 = (lane & 3) * 4;
  float4 p4[8];
  #pragma unroll
  for (int b = 0; b < 8; ++b)
    p4[b] = *(const float4*)&x[((size_t)b * 256 + pi * 16 + r) * 256 + pj * 16 + c0];

  for (int h = hb + w; h < hb + 64; h += 4) {
    const float4 w4 = *(const float4*)&pw[((size_t)h * 256 + n) * 256 + lane * 4];
    float part[8];
    #pragma unroll
    for (int b = 0; b < 8; ++b)
      part[b] = fmaf(p4[b].x, w4.x, fmaf(p4[b].y, w4.y, fmaf(p4[b].z, w4.z, p4[b].w * w4.w)));
    #pragma unroll
    for (int m = 1; m < 64; m <<= 1) {
      #pragma unroll
      for (int b = 0; b < 8; ++b) part[b] += __shfl_xor(part[b], m, 64);
    }
    if (lane < 8) {
      float addend = pb[h * 256 + n] + pos[(1 + h) * 256 + n];
      t[((size_t)lane * S + 1 + h) * D + n] = part[lane] + addend;
    }
  }
}

// ---------------- layernorm: one wave per row of 256 ----------------
__global__ __launch_bounds__(256) void ln_kernel(const float* __restrict__ in,
                                                 float* __restrict__ out,
                                                 const float* __restrict__ g,
                                                 const float* __restrict__ b,
                                                 int nrows) {
  int wid = threadIdx.x >> 6, lane = threadIdx.x & 63;
  int row = blockIdx.x * 4 + wid;
  if (row >= nrows) return;
  const float* p = in + (size_t)row * D;
  float4 v = *(const float4*)&p[lane * 4];
  float s = wave_sum(v.x + v.y + v.z + v.w);
  float mu = s * (1.0f / 256.0f);
  float dx = v.x - mu, dy = v.y - mu, dz = v.z - mu, dw = v.w - mu;
  float q = wave_sum(dx * dx + dy * dy + dz * dz + dw * dw);
  float rs = 1.0f / sqrtf(q * (1.0f / 256.0f) + 1e-5f);
  float4 gv = *(const float4*)&g[lane * 4];
  float4 bv = *(const float4*)&b[lane * 4];
  float4 o;
  o.x = dx * rs * gv.x + bv.x;
  o.y = dy * rs * gv.y + bv.y;
  o.z = dz * rs * gv.z + bv.z;
  o.w = dw * rs * gv.w + bv.w;
  *(float4*)&out[(size_t)row * D + lane * 4] = o;
}

// ---------------- generic fp32 GEMM, 64x64 tile, 256 thr, 4x4/thread ----------------
// BT=1: B given as [N,K] row-major (i.e. B^T). RES: add res[r,c]. GELU: exact gelu.
template<int BT, int RES, int GELU>
__device__ __forceinline__ void gemm_body(const float* __restrict__ A,
                                          const float* __restrict__ B,
                                          const float* __restrict__ bias,
                                          const float* __restrict__ res,
                                          float* __restrict__ C,
                                          int M, int N, int K) {
  __shared__ __align__(16) float As[16][68];
  __shared__ __align__(16) float Bs[16][68];
  const int tid = threadIdx.x;
  const int tm = tid >> 4, tn = tid & 15;
  const int row0 = blockIdx.y * 64, col0 = blockIdx.x * 64;

  const int ar = tid >> 2;           // 0..63
  const int ak = (tid & 3) * 4;      // 0,4,8,12
  int arow = row0 + ar; if (arow >= M) arow = M - 1;

  float acc[4][4] = {};

  for (int k0 = 0; k0 < K; k0 += 16) {
    float4 av = *(const float4*)&A[(size_t)arow * K + k0 + ak];
    float4 bv;
    if (BT) bv = *(const float4*)&B[(size_t)(col0 + ar) * K + k0 + ak];
    else    bv = *(const float4*)&B[(size_t)(k0 + tm) * N + col0 + tn * 4];
    __syncthreads();
    As[ak + 0][ar] = av.x; As[ak + 1][ar] = av.y;
    As[ak + 2][ar] = av.z; As[ak + 3][ar] = av.w;
    if (BT) {
      Bs[ak + 0][ar] = bv.x; Bs[ak + 1][ar] = bv.y;
      Bs[ak + 2][ar] = bv.z; Bs[ak + 3][ar] = bv.w;
    } else {
      *(float4*)&Bs[tm][tn * 4] = bv;
    }
    __syncthreads();
    #pragma unroll
    for (int k = 0; k < 16; ++k) {
      const float4 a4 = *(const float4*)&As[k][tm * 4];
      const float4 b4 = *(const float4*)&Bs[k][tn * 4];
      const float aa[4] = {a4.x, a4.y, a4.z, a4.w};
      const float bb[4] = {b4.x, b4.y, b4.z, b4.w};
      #pragma unroll
      for (int i = 0; i < 4; ++i)
        #pragma unroll
        for (int j = 0; j < 4; ++j)
          acc[i][j] = fmaf(aa[i], bb[j], acc[i][j]);
    }
  }

  #pragma unroll
  for (int i = 0; i < 4; ++i) {
    int rrow = row0 + tm * 4 + i;
    if (rrow >= M) continue;
    #pragma unroll
    for (int j = 0; j < 4; ++j) {
      int c = col0 + tn * 4 + j;
      float vv = acc[i][j];
      if (bias) vv += bias[c];
      if (GELU) vv = 0.5f * vv * (1.0f + erff(vv * 0.70710678118654752440f));
      if (RES)  vv += res[(size_t)rrow * N + c];
      C[(size_t)rrow * N + c] = vv;
    }
  }
}

template<int BT, int RES, int GELU>
__global__ __launch_bounds__(256) void gemm64(const float* __restrict__ A,
                                              const float* __restrict__ B,
                                              const float* __restrict__ bias,
                                              const float* __restrict__ res,
                                              float* __restrict__ C,
                                              int M, int N, int K) {
  gemm_body<BT, RES, GELU>(A, B, bias, res, C, M, N, K);
}

// QKV: one launch, blockIdx.z selects weight/output. Weights are [H,D] = [N,K] (BT).
__global__ __launch_bounds__(256) void qkv_kernel(const float* __restrict__ A,
                                                  const float* __restrict__ wq,
                                                  const float* __restrict__ wk,
                                                  const float* __restrict__ wv,
                                                  float* __restrict__ q,
                                                  float* __restrict__ k,
                                                  float* __restrict__ v) {
  const float* B = blockIdx.z == 0 ? wq : blockIdx.z == 1 ? wk : wv;
  float*       C = blockIdx.z == 0 ? q  : blockIdx.z == 1 ? k  : v;
  gemm_body<1, 0, 0>(A, B, nullptr, nullptr, C, M_ROWS, 256, 256);
}

// ---------------- attention (d_head = 1) ----------------
// per (b,h): o[s] = sum_t softmax_t(q_s * k_t) * v_t
__global__ __launch_bounds__(256) void attn_kernel(const float* __restrict__ Q,
                                                   const float* __restrict__ Kb,
                                                   const float* __restrict__ Vb,
                                                   float* __restrict__ O) {
  __shared__ float ks[S], vs[S];
  __shared__ float red[8];
  int h = blockIdx.x, b = blockIdx.y;
  size_t base = ((size_t)b * S) * D + h;
  int tid = threadIdx.x;
  for (int s = tid; s < S; s += 256) {
    ks[s] = Kb[base + (size_t)s * D];
    vs[s] = Vb[base + (size_t)s * D];
  }
  __syncthreads();
  float lmax = -1e30f, lmin = 1e30f;
  for (int s = tid; s < S; s += 256) {
    float kv = ks[s];
    lmax = fmaxf(lmax, kv); lmin = fminf(lmin, kv);
  }
  #pragma unroll
  for (int m = 1; m < 64; m <<= 1) {
    lmax = fmaxf(lmax, __shfl_xor(lmax, m, 64));
    lmin = fminf(lmin, __shfl_xor(lmin, m, 64));
  }
  int wid = tid >> 6, lane = tid & 63;
  if (lane == 0) { red[wid] = lmax; red[4 + wid] = lmin; }
  __syncthreads();
  float kmax = fmaxf(fmaxf(red[0], red[1]), fmaxf(red[2], red[3]));
  float kmin = fminf(fminf(red[4], red[5]), fminf(red[6], red[7]));

  const float L2E = 1.4426950408889634f;
  for (int s = tid; s < S; s += 256) {
    float qv = Q[base + (size_t)s * D];
    float mm = qv >= 0.0f ? qv * kmax : qv * kmin;
    float ql = qv * L2E, ml = mm * L2E;
    float den = 0.0f, num = 0.0f;
    for (int u = 0; u < S; ++u) {
      float e = exp2f(fmaf(ql, ks[u], -ml));
      den += e;
      num = fmaf(e, vs[u], num);
    }
    O[base + (size_t)s * D] = num / den;
  }
}

// ---------------- head: logits = t[:,0,:] @ head_w + head_b ; softmax ----------------
__global__ __launch_bounds__(256) void head_kernel(const float* __restrict__ t,
                                                   const float* __restrict__ hw,
                                                   const float* __restrict__ hb,
                                                   float* __restrict__ out) {
  __shared__ float trow[D];
  __shared__ float lg[NCLS];
  __shared__ float red[8];
  int b = blockIdx.x, tid = threadIdx.x;
  trow[tid] = t[((size_t)b * S) * D + tid];
  __syncthreads();
  for (int n = tid; n < NCLS; n += 256) {
    float acc = hb[n];
    for (int d = 0; d < D; ++d) acc = fmaf(trow[d], hw[(size_t)d * NCLS + n], acc);
    lg[n] = acc;
  }
  __syncthreads();
  float lmax = -1e30f;
  for (int n = tid; n < NCLS; n += 256) lmax = fmaxf(lmax, lg[n]);
  #pragma unroll
  for (int m = 1; m < 64; m <<= 1) lmax = fmaxf(lmax, __shfl_xor(lmax, m, 64));
  int wid = tid >> 6, lane = tid & 63;
  if (lane == 0) red[wid] = lmax;
  __syncthreads();
  float gmax = fmaxf(fmaxf(red[0], red[1]), fmaxf(red[2], red[3]));
  float lsum = 0.0f;
  for (int n = tid; n < NCLS; n += 256) {
    float e = expf(lg[n] - gmax);
    lg[n] = e;
    lsum += e;
  }
  lsum = wave_sum(lsum);
  if (lane == 0) red[4 + wid] = lsum;
  __syncthreads();
  float inv = 1.0f / (red[4] + red[5] + red[6] + red[7]);
  for (int n = tid; n < NCLS; n += 256) out[(size_t)b * NCLS + n] = lg[n] * inv;
}

// ---------------- launch ----------------
extern "C" void kernel_launch(void* const* d_in, const int* in_sizes, int n_in,
                              void* d_out, int out_size, void* d_ws, size_t ws_size,
                              hipStream_t stream) {
  const float* x        = (const float*)d_in[0];
  const float* class_tk = (const float*)d_in[1];
  const float* pos_emb  = (const float*)d_in[2];
  const float* patch_w  = (const float*)d_in[3];
  const float* patch_b  = (const float*)d_in[4];
  const float* wq       = (const float*)d_in[5];
  const float* wk       = (const float*)d_in[6];
  const float* wv       = (const float*)d_in[7];
  const float* proj_w   = (const float*)d_in[8];
  const float* proj_b   = (const float*)d_in[9];
  const float* mlp_w1   = (const float*)d_in[10];
  const float* mlp_b1   = (const float*)d_in[11];
  const float* mlp_w2   = (const float*)d_in[12];
  const float* mlp_b2   = (const float*)d_in[13];
  const float* ln1_g    = (const float*)d_in[14];
  const float* ln1_b    = (const float*)d_in[15];
  const float* ln2_g    = (const float*)d_in[16];
  const float* ln2_b    = (const float*)d_in[17];
  const float* head_w   = (const float*)d_in[18];
  const float* head_b   = (const float*)d_in[19];
  float* out = (float*)d_out;

  float* ws = (float*)d_ws;
  const size_t NTOK = (size_t)M_ROWS * D;   // 526336
  float* t  = ws;
  float* xn = ws + NTOK;
  float* q  = ws + 2 * NTOK;
  float* kk = ws + 3 * NTOK;
  float* v  = ws + 4 * NTOK;
  float* o  = ws + 5 * NTOK;
  float* h1 = ws + 2 * NTOK;                // reuse q/kk/v/o region (dead by mlp1)

  cls_kernel<<<Bsz, 256, 0, stream>>>(class_tk, pos_emb, t);
  patch_kernel<<<1024, 256, 0, stream>>>(x, patch_w, patch_b, pos_emb, t);
  ln_kernel<<<(M_ROWS + 3) / 4, 256, 0, stream>>>(t, xn, ln1_g, ln1_b, M_ROWS);

  dim3 gq(4, 33, 3);
  qkv_kernel<<<gq, 256, 0, stream>>>(xn, wq, wk, wv, q, kk, v);

  dim3 ga(256, Bsz);
  attn_kernel<<<ga, 256, 0, stream>>>(q, kk, v, o);

  dim3 gp(4, 33);
  gemm64<0, 1, 0><<<gp, 256, 0, stream>>>(o, proj_w, proj_b, t, t, M_ROWS, 256, 256);

  ln_kernel<<<(M_ROWS + 3) / 4, 256, 0, stream>>>(t, xn, ln2_g, ln2_b, M_ROWS);

  dim3 gm1(16, 33);
  gemm64<0, 0, 1><<<gm1, 256, 0, stream>>>(xn, mlp_w1, mlp_b1, nullptr, h1, M_ROWS, MLP, 256);

  dim3 gm2(4, 33);
  gemm64<0, 1, 0><<<gm2, 256, 0, stream>>>(h1, mlp_w2, mlp_b2, t, t, M_ROWS, 256, MLP);

  head_kernel<<<Bsz, 256, 0, stream>>>(t, head_w, head_b, out);
}

// Round 2
// 184.934 us; speedup vs baseline: 1.4493x; 1.4493x over previous
//
#include <hip/hip_runtime.h>
#include <math.h>

// ---------------- constants ----------------
#define Bsz   8
#define CHUNK 16
#define D     256      // d_model = num_heads = num_patches = 256
#define S     257      // seq len
#define MLP   1024
#define NCLS  1000
#define M_ROWS (Bsz * S)   // 2056

typedef unsigned int u32;
typedef unsigned short u16;
typedef __attribute__((ext_vector_type(8))) short bshort8;
typedef __attribute__((ext_vector_type(4))) float f32x4;

__device__ __forceinline__ float wave_sum(float v) {
  #pragma unroll
  for (int m = 1; m < 64; m <<= 1) v += __shfl_xor(v, m, 64);
  return v;
}

__device__ __forceinline__ u16 f2bf(float f) {
  u32 u = __float_as_uint(f);
  u += 0x7FFFu + ((u >> 16) & 1u);   // RNE
  return (u16)(u >> 16);
}
__device__ __forceinline__ float bf2f(u16 h) { return __uint_as_float(((u32)h) << 16); }
__device__ __forceinline__ u32 pk2(u16 a, u16 b) { return (u32)a | ((u32)b << 16); }

// ---------------- cls row ----------------
__global__ __launch_bounds__(256) void cls_kernel(const float* __restrict__ ct,
                                                  const float* __restrict__ pos,
                                                  float* __restrict__ t) {
  int b = blockIdx.x, d = threadIdx.x;
  t[((size_t)b * S) * D + d] = ct[d] + pos[d];
}

// ---------------- patch embed ----------------
__global__ __launch_bounds__(256) void patch_kernel(const float* __restrict__ x,
                                                    const float* __restrict__ pw,
                                                    const float* __restrict__ pb,
                                                    const float* __restrict__ pos,
                                                    float* __restrict__ t) {
  int n  = blockIdx.x & 255;
  int hb = (blockIdx.x >> 8) * 64;
  int pi = n >> 4, pj = n & 15;
  int lane = threadIdx.x & 63, w = threadIdx.x >> 6;
  int r = lane >> 2, c0 = (lane & 3) * 4;
  float4 p4[8];
  #pragma unroll
  for (int b = 0; b < 8; ++b)
    p4[b] = *(const float4*)&x[((size_t)b * 256 + pi * 16 + r) * 256 + pj * 16 + c0];

  for (int h = hb + w; h < hb + 64; h += 4) {
    const float4 w4 = *(const float4*)&pw[((size_t)h * 256 + n) * 256 + lane * 4];
    float part[8];
    #pragma unroll
    for (int b = 0; b < 8; ++b)
      part[b] = fmaf(p4[b].x, w4.x, fmaf(p4[b].y, w4.y, fmaf(p4[b].z, w4.z, p4[b].w * w4.w)));
    #pragma unroll
    for (int m = 1; m < 64; m <<= 1) {
      #pragma unroll
      for (int b = 0; b < 8; ++b) part[b] += __shfl_xor(part[b], m, 64);
    }
    if (lane < 8) {
      float addend = pb[h * 256 + n] + pos[(1 + h) * 256 + n];
      t[((size_t)lane * S + 1 + h) * D + n] = part[lane] + addend;
    }
  }
}

// ---------------- layernorm: one wave per row of 256 ----------------
__global__ __launch_bounds__(256) void ln_kernel(const float* __restrict__ in,
                                                 float* __restrict__ out,
                                                 const float* __restrict__ g,
                                                 const float* __restrict__ b,
                                                 int nrows) {
  int wid = threadIdx.x >> 6, lane = threadIdx.x & 63;
  int row = blockIdx.x * 4 + wid;
  if (row >= nrows) return;
  const float* p = in + (size_t)row * D;
  float4 v = *(const float4*)&p[lane * 4];
  float s = wave_sum(v.x + v.y + v.z + v.w);
  float mu = s * (1.0f / 256.0f);
  float dx = v.x - mu, dy = v.y - mu, dz = v.z - mu, dw = v.w - mu;
  float q = wave_sum(dx * dx + dy * dy + dz * dz + dw * dw);
  float rs = 1.0f / sqrtf(q * (1.0f / 256.0f) + 1e-5f);
  float4 gv = *(const float4*)&g[lane * 4];
  float4 bv = *(const float4*)&b[lane * 4];
  float4 o;
  o.x = dx * rs * gv.x + bv.x;
  o.y = dy * rs * gv.y + bv.y;
  o.z = dz * rs * gv.z + bv.z;
  o.w = dw * rs * gv.w + bv.w;
  *(float4*)&out[(size_t)row * D + lane * 4] = o;
}

// ---------------- weight conversion kernels ----------------
// copy-convert: src fp32 [R=256][C=256] -> oh/ol bf16 same layout (one 32x32 tile/block)
__global__ __launch_bounds__(256) void conv_copy3(const float* __restrict__ wq,
                                                  const float* __restrict__ wk,
                                                  const float* __restrict__ wv,
                                                  u16* __restrict__ W) {
  int wsel = blockIdx.x >> 6, tile = blockIdx.x & 63;
  const float* src = wsel == 0 ? wq : wsel == 1 ? wk : wv;
  u16* oh = W + wsel * 131072;
  u16* ol = oh + 65536;
  int r0 = (tile >> 3) * 32, c0 = (tile & 7) * 32;
  int tr = threadIdx.x >> 3, tc = (threadIdx.x & 7) * 4;
  const float4 f = *(const float4*)(src + (size_t)(r0 + tr) * 256 + c0 + tc);
  u16 h0 = f2bf(f.x), h1 = f2bf(f.y), h2 = f2bf(f.z), h3 = f2bf(f.w);
  u16 l0 = f2bf(f.x - bf2f(h0)), l1 = f2bf(f.y - bf2f(h1));
  u16 l2 = f2bf(f.z - bf2f(h2)), l3 = f2bf(f.w - bf2f(h3));
  size_t o = (size_t)(r0 + tr) * 256 + c0 + tc;
  *(uint2*)(oh + o) = make_uint2(pk2(h0, h1), pk2(h2, h3));
  *(uint2*)(ol + o) = make_uint2(pk2(l0, l1), pk2(l2, l3));
}

// transpose-convert: src fp32 [R][C] -> oh/ol bf16 [C][R]
__global__ __launch_bounds__(256) void conv_trans(const float* __restrict__ src,
                                                  u16* __restrict__ oh,
                                                  u16* __restrict__ ol,
                                                  int R, int Cc) {
  __shared__ float lt[32][33];
  int tpc = Cc >> 5;
  int r0 = (blockIdx.x / tpc) * 32, c0 = (blockIdx.x % tpc) * 32;
  int tr = threadIdx.x >> 3, tc = (threadIdx.x & 7) * 4;
  float4 f = *(const float4*)(src + (size_t)(r0 + tr) * Cc + c0 + tc);
  lt[tr][tc + 0] = f.x; lt[tr][tc + 1] = f.y; lt[tr][tc + 2] = f.z; lt[tr][tc + 3] = f.w;
  __syncthreads();
  float a = lt[tc + 0][tr], b = lt[tc + 1][tr], c = lt[tc + 2][tr], d = lt[tc + 3][tr];
  u16 h0 = f2bf(a), h1 = f2bf(b), h2 = f2bf(c), h3 = f2bf(d);
  u16 l0 = f2bf(a - bf2f(h0)), l1 = f2bf(b - bf2f(h1));
  u16 l2 = f2bf(c - bf2f(h2)), l3 = f2bf(d - bf2f(h3));
  size_t o = (size_t)(c0 + tr) * R + r0 + tc;
  *(uint2*)(oh + o) = make_uint2(pk2(h0, h1), pk2(h2, h3));
  *(uint2*)(ol + o) = make_uint2(pk2(l0, l1), pk2(l2, l3));
}

// ---------------- MFMA split-bf16 GEMM ----------------
// C[m][n] = sum_k A[m][k] * W[n][k]   (W given split bf16 [N][K])
// AMODE 0: A fp32, split in staging (3 mfma). AMODE 1: A bf16 single [M][K] (2 mfma).
// 64x64 tile, BK=64, 256 threads (4 waves, 32x32 quadrant each), XOR-swizzled LDS.
template<int AMODE, int HASBIAS, int RES, int GELU, int OUTBF>
__device__ __forceinline__ void gemm_core(const float* __restrict__ A32,
                                          const u16* __restrict__ A16,
                                          const u16* __restrict__ Bh,
                                          const u16* __restrict__ Bl,
                                          const float* __restrict__ bias,
                                          const float* __restrict__ res,
                                          float* __restrict__ Cf,
                                          u16* __restrict__ C16,
                                          int M, int N, int K, int row0, int col0) {
  __shared__ __align__(16) u16 sAh[4096];
  __shared__ __align__(16) u16 sAl[AMODE == 0 ? 4096 : 8];
  __shared__ __align__(16) u16 sBh[4096];
  __shared__ __align__(16) u16 sBl[4096];
  const int tid = threadIdx.x;
  const int lane = tid & 63;
  const int w = tid >> 6, wm = w >> 1, wn = w & 1;
  const int fr = lane & 15, g = lane >> 4;
  const int sr = tid >> 2, sc = tid & 3;
  int arow = row0 + sr; if (arow > M - 1) arow = M - 1;
  const u32 off0 = (u32)(sr * 128) + ((u32)((2 * sc)     ^ (sr & 7)) << 4);
  const u32 off1 = (u32)(sr * 128) + ((u32)((2 * sc + 1) ^ (sr & 7)) << 4);
  const float* ap32 = nullptr; const u16* ap16 = nullptr;
  if (AMODE == 0) ap32 = A32 + (size_t)arow * K + sc * 16;
  else            ap16 = A16 + (size_t)arow * K + sc * 16;
  const u16* bhp = Bh + (size_t)(col0 + sr) * K + sc * 16;
  const u16* blp = Bl + (size_t)(col0 + sr) * K + sc * 16;

  f32x4 acc[2][2], ac2[2][2];
  #pragma unroll
  for (int i = 0; i < 2; ++i)
    #pragma unroll
    for (int j = 0; j < 2; ++j) { acc[i][j] = (f32x4){0,0,0,0}; ac2[i][j] = (f32x4){0,0,0,0}; }

  for (int k0 = 0; k0 < K; k0 += 64) {
    uint4 wAh0, wAh1, wAl0, wAl1;
    if (AMODE == 0) {
      float fv[16];
      #pragma unroll
      for (int i = 0; i < 4; ++i) {
        float4 f4 = *(const float4*)(ap32 + k0 + i * 4);
        fv[i*4+0] = f4.x; fv[i*4+1] = f4.y; fv[i*4+2] = f4.z; fv[i*4+3] = f4.w;
      }
      u16 hh[16], ll[16];
      #pragma unroll
      for (int i = 0; i < 16; ++i) { u16 h = f2bf(fv[i]); hh[i] = h; ll[i] = f2bf(fv[i] - bf2f(h)); }
      wAh0 = make_uint4(pk2(hh[0],hh[1]), pk2(hh[2],hh[3]), pk2(hh[4],hh[5]), pk2(hh[6],hh[7]));
      wAh1 = make_uint4(pk2(hh[8],hh[9]), pk2(hh[10],hh[11]), pk2(hh[12],hh[13]), pk2(hh[14],hh[15]));
      wAl0 = make_uint4(pk2(ll[0],ll[1]), pk2(ll[2],ll[3]), pk2(ll[4],ll[5]), pk2(ll[6],ll[7]));
      wAl1 = make_uint4(pk2(ll[8],ll[9]), pk2(ll[10],ll[11]), pk2(ll[12],ll[13]), pk2(ll[14],ll[15]));
    } else {
      wAh0 = *(const uint4*)(ap16 + k0);
      wAh1 = *(const uint4*)(ap16 + k0 + 8);
      wAl0 = wAh0; wAl1 = wAh1; // unused
    }
    uint4 wBh0 = *(const uint4*)(bhp + k0);
    uint4 wBh1 = *(const uint4*)(bhp + k0 + 8);
    uint4 wBl0 = *(const uint4*)(blp + k0);
    uint4 wBl1 = *(const uint4*)(blp + k0 + 8);
    __syncthreads();
    *(uint4*)((char*)sAh + off0) = wAh0;
    *(uint4*)((char*)sAh + off1) = wAh1;
    if (AMODE == 0) {
      *(uint4*)((char*)sAl + off0) = wAl0;
      *(uint4*)((char*)sAl + off1) = wAl1;
    }
    *(uint4*)((char*)sBh + off0) = wBh0;
    *(uint4*)((char*)sBh + off1) = wBh1;
    *(uint4*)((char*)sBl + off0) = wBl0;
    *(uint4*)((char*)sBl + off1) = wBl1;
    __syncthreads();
    #pragma unroll
    for (int ks = 0; ks < 2; ++ks) {
      bshort8 ah[2], al[2], bh2[2], bl2[2];
      #pragma unroll
      for (int f = 0; f < 2; ++f) {
        int rA = wm * 32 + f * 16 + fr;
        u32 oa = (u32)(rA * 128) + ((u32)((ks * 4 + g) ^ (rA & 7)) << 4);
        ah[f] = *(const bshort8*)((const char*)sAh + oa);
        if (AMODE == 0) al[f] = *(const bshort8*)((const char*)sAl + oa);
        int rB = wn * 32 + f * 16 + fr;
        u32 ob = (u32)(rB * 128) + ((u32)((ks * 4 + g) ^ (rB & 7)) << 4);
        bh2[f] = *(const bshort8*)((const char*)sBh + ob);
        bl2[f] = *(const bshort8*)((const char*)sBl + ob);
      }
      #pragma unroll
      for (int fi = 0; fi < 2; ++fi)
        #pragma unroll
        for (int fj = 0; fj < 2; ++fj) {
          acc[fi][fj] = __builtin_amdgcn_mfma_f32_16x16x32_bf16(ah[fi], bh2[fj], acc[fi][fj], 0, 0, 0);
          ac2[fi][fj] = __builtin_amdgcn_mfma_f32_16x16x32_bf16(ah[fi], bl2[fj], ac2[fi][fj], 0, 0, 0);
          if (AMODE == 0)
            ac2[fi][fj] = __builtin_amdgcn_mfma_f32_16x16x32_bf16(al[fi], bh2[fj], ac2[fi][fj], 0, 0, 0);
        }
    }
  }
  // epilogue: D[row][col], row = 4*(lane>>4)+reg, col = lane&15 within 16x16 frag
  #pragma unroll
  for (int fi = 0; fi < 2; ++fi) {
    #pragma unroll
    for (int fj = 0; fj < 2; ++fj) {
      int col = col0 + wn * 32 + fj * 16 + fr;
      int rbase = row0 + wm * 32 + fi * 16 + g * 4;
      #pragma unroll
      for (int r = 0; r < 4; ++r) {
        int row = rbase + r;
        if (row < M) {
          float v = acc[fi][fj][r] + ac2[fi][fj][r];
          if (HASBIAS) v += bias[col];
          if (GELU) v = 0.5f * v * (1.0f + erff(v * 0.70710678118654752440f));
          if (RES)  v += res[(size_t)row * N + col];
          if (OUTBF) C16[(size_t)row * N + col] = f2bf(v);
          else       Cf[(size_t)row * N + col] = v;
        }
      }
    }
  }
}

template<int AMODE, int HASBIAS, int RES, int GELU, int OUTBF>
__global__ __launch_bounds__(256) void gemm_k(const float* __restrict__ A32,
                                              const u16* __restrict__ A16,
                                              const u16* __restrict__ Bh,
                                              const u16* __restrict__ Bl,
                                              const float* __restrict__ bias,
                                              const float* __restrict__ res,
                                              float* __restrict__ Cf,
                                              u16* __restrict__ C16,
                                              int M, int N, int K) {
  gemm_core<AMODE, HASBIAS, RES, GELU, OUTBF>(A32, A16, Bh, Bl, bias, res, Cf, C16,
                                              M, N, K, blockIdx.y * 64, blockIdx.x * 64);
}

// QKV: z selects weight/output; weights packed [wqh,wql,wkh,wkl,wvh,wvl] (65536 u16 each)
__global__ __launch_bounds__(256) void qkv_kernel(const float* __restrict__ xn,
                                                  const u16* __restrict__ W,
                                                  float* __restrict__ q,
                                                  float* __restrict__ k,
                                                  float* __restrict__ v) {
  int z = blockIdx.z;
  const u16* Bh = W + z * 131072;
  const u16* Bl = Bh + 65536;
  float* C = z == 0 ? q : z == 1 ? k : v;
  gemm_core<0, 0, 0, 0, 0>(xn, nullptr, Bh, Bl, nullptr, nullptr, C, nullptr,
                           M_ROWS, 256, 256, blockIdx.y * 64, blockIdx.x * 64);
}

// ---------------- attention (d_head = 1) ----------------
__global__ __launch_bounds__(256) void attn_kernel(const float* __restrict__ Q,
                                                   const float* __restrict__ Kb,
                                                   const float* __restrict__ Vb,
                                                   float* __restrict__ O) {
  __shared__ float ks[S], vs[S];
  __shared__ float red[8];
  int h = blockIdx.x, b = blockIdx.y;
  size_t base = ((size_t)b * S) * D + h;
  int tid = threadIdx.x;
  for (int s = tid; s < S; s += 256) {
    ks[s] = Kb[base + (size_t)s * D];
    vs[s] = Vb[base + (size_t)s * D];
  }
  __syncthreads();
  float lmax = -1e30f, lmin = 1e30f;
  for (int s = tid; s < S; s += 256) {
    float kv = ks[s];
    lmax = fmaxf(lmax, kv); lmin = fminf(lmin, kv);
  }
  #pragma unroll
  for (int m = 1; m < 64; m <<= 1) {
    lmax = fmaxf(lmax, __shfl_xor(lmax, m, 64));
    lmin = fminf(lmin, __shfl_xor(lmin, m, 64));
  }
  int wid = tid >> 6, lane = tid & 63;
  if (lane == 0) { red[wid] = lmax; red[4 + wid] = lmin; }
  __syncthreads();
  float kmax = fmaxf(fmaxf(red[0], red[1]), fmaxf(red[2], red[3]));
  float kmin = fminf(fminf(red[4], red[5]), fminf(red[6], red[7]));

  const float L2E = 1.4426950408889634f;
  for (int s = tid; s < S; s += 256) {
    float qv = Q[base + (size_t)s * D];
    float mm = qv >= 0.0f ? qv * kmax : qv * kmin;
    float ql = qv * L2E, ml = mm * L2E;
    float den = 0.0f, num = 0.0f;
    for (int u = 0; u < S; ++u) {
      float e = exp2f(fmaf(ql, ks[u], -ml));
      den += e;
      num = fmaf(e, vs[u], num);
    }
    O[base + (size_t)s * D] = num / den;
  }
}

// ---------------- head: logits + softmax, 1024 threads ----------------
__global__ __launch_bounds__(1024) void head_kernel(const float* __restrict__ t,
                                                    const float* __restrict__ hw,
                                                    const float* __restrict__ hb,
                                                    float* __restrict__ out) {
  __shared__ float trow[D];
  __shared__ float red[16];
  int b = blockIdx.x, tid = threadIdx.x;
  if (tid < D) trow[tid] = t[((size_t)b * S) * D + tid];
  __syncthreads();
  float acc = 0.0f;
  int n = tid;
  if (n < NCLS) {
    acc = hb[n];
    for (int d = 0; d < D; ++d) acc = fmaf(trow[d], hw[(size_t)d * NCLS + n], acc);
  }
  float m = (n < NCLS) ? acc : -1e30f;
  #pragma unroll
  for (int s = 1; s < 64; s <<= 1) m = fmaxf(m, __shfl_xor(m, s, 64));
  int wid = tid >> 6, lane = tid & 63;
  if (lane == 0) red[wid] = m;
  __syncthreads();
  if (tid == 0) {
    float mm = red[0];
    #pragma unroll
    for (int i = 1; i < 16; ++i) mm = fmaxf(mm, red[i]);
    red[0] = mm;
  }
  __syncthreads();
  float gmax = red[0];
  float e = (n < NCLS) ? expf(acc - gmax) : 0.0f;
  float ss = e;
  #pragma unroll
  for (int s = 1; s < 64; s <<= 1) ss += __shfl_xor(ss, s, 64);
  __syncthreads();
  if (lane == 0) red[wid] = ss;
  __syncthreads();
  if (tid == 0) {
    float t2 = 0.0f;
    #pragma unroll
    for (int i = 0; i < 16; ++i) t2 += red[i];
    red[0] = t2;
  }
  __syncthreads();
  if (n < NCLS) out[(size_t)b * NCLS + n] = e / red[0];
}

// ---------------- launch ----------------
extern "C" void kernel_launch(void* const* d_in, const int* in_sizes, int n_in,
                              void* d_out, int out_size, void* d_ws, size_t ws_size,
                              hipStream_t stream) {
  const float* x        = (const float*)d_in[0];
  const float* class_tk = (const float*)d_in[1];
  const float* pos_emb  = (const float*)d_in[2];
  const float* patch_w  = (const float*)d_in[3];
  const float* patch_b  = (const float*)d_in[4];
  const float* wq       = (const float*)d_in[5];
  const float* wk       = (const float*)d_in[6];
  const float* wv       = (const float*)d_in[7];
  const float* proj_w   = (const float*)d_in[8];
  const float* proj_b   = (const float*)d_in[9];
  const float* mlp_w1   = (const float*)d_in[10];
  const float* mlp_b1   = (const float*)d_in[11];
  const float* mlp_w2   = (const float*)d_in[12];
  const float* mlp_b2   = (const float*)d_in[13];
  const float* ln1_g    = (const float*)d_in[14];
  const float* ln1_b    = (const float*)d_in[15];
  const float* ln2_g    = (const float*)d_in[16];
  const float* ln2_b    = (const float*)d_in[17];
  const float* head_w   = (const float*)d_in[18];
  const float* head_b   = (const float*)d_in[19];
  float* out = (float*)d_out;

  float* ws = (float*)d_ws;
  const size_t NTOK = (size_t)M_ROWS * D;   // 526336
  // region map (floats) — total 6*NTOK = 12.6 MB (proven available):
  // t: 0..N | xn: N..2N | q: 2N..3N | k: 3N..4N | v: 4N..5N | o: 5N..6N
  // time-shared: Wqkv bf16 @5N (dead after attn writes o); W1 bf16 @2N (q dead after attn);
  // Wpj bf16 @4N (v dead after attn, used by proj); H1 bf16 single @3N..5N (mlp1->mlp2);
  // W2 bf16 @N (xn dead after mlp1).
  float* t  = ws;
  float* xn = ws + NTOK;
  float* q  = ws + 2 * NTOK;
  float* kk = ws + 3 * NTOK;
  float* v  = ws + 4 * NTOK;
  float* o  = ws + 5 * NTOK;
  u16* Wqkv = (u16*)(ws + 5 * NTOK);   // 6*65536 u16
  u16* W1   = (u16*)(ws + 2 * NTOK);   // 2*262144 u16
  u16* Wpj  = (u16*)(ws + 4 * NTOK);   // 2*65536 u16
  u16* H1   = (u16*)(ws + 3 * NTOK);   // 2056*1024 u16
  u16* W2   = (u16*)(ws + 1 * NTOK);   // 2*262144 u16

  conv_copy3<<<192, 256, 0, stream>>>(wq, wk, wv, Wqkv);
  cls_kernel<<<Bsz, 256, 0, stream>>>(class_tk, pos_emb, t);
  patch_kernel<<<1024, 256, 0, stream>>>(x, patch_w, patch_b, pos_emb, t);
  ln_kernel<<<(M_ROWS + 3) / 4, 256, 0, stream>>>(t, xn, ln1_g, ln1_b, M_ROWS);

  qkv_kernel<<<dim3(4, 33, 3), 256, 0, stream>>>(xn, Wqkv, q, kk, v);

  attn_kernel<<<dim3(256, Bsz), 256, 0, stream>>>(q, kk, v, o);

  conv_trans<<<64, 256, 0, stream>>>(proj_w, Wpj, Wpj + 65536, 256, 256);
  conv_trans<<<256, 256, 0, stream>>>(mlp_w1, W1, W1 + 262144, 256, 1024);

  gemm_k<0, 1, 1, 0, 0><<<dim3(4, 33), 256, 0, stream>>>(
      o, nullptr, Wpj, Wpj + 65536, proj_b, t, t, nullptr, M_ROWS, 256, 256);

  ln_kernel<<<(M_ROWS + 3) / 4, 256, 0, stream>>>(t, xn, ln2_g, ln2_b, M_ROWS);

  gemm_k<0, 1, 0, 1, 1><<<dim3(16, 33), 256, 0, stream>>>(
      xn, nullptr, W1, W1 + 262144, mlp_b1, nullptr, nullptr, H1, M_ROWS, MLP, 256);

  conv_trans<<<256, 256, 0, stream>>>(mlp_w2, W2, W2 + 262144, 1024, 256);

  gemm_k<1, 1, 1, 0, 0><<<dim3(4, 33), 256, 0, stream>>>(
      nullptr, H1, W2, W2 + 262144, mlp_b2, t, t, nullptr, M_ROWS, 256, MLP);

  head_kernel<<<Bsz, 1024, 0, stream>>>(t, head_w, head_b, out);
}

// Round 3
// 167.777 us; speedup vs baseline: 1.5975x; 1.1023x over previous
//
#include <hip/hip_runtime.h>
#include <math.h>

// ---------------- constants ----------------
#define Bsz   8
#define CHUNK 16
#define D     256      // d_model = num_heads = num_patches = 256
#define S     257      // seq len
#define MLP   1024
#define NCLS  1000
#define M_ROWS (Bsz * S)   // 2056

typedef unsigned int u32;
typedef unsigned short u16;
typedef __attribute__((ext_vector_type(8))) short bshort8;
typedef __attribute__((ext_vector_type(4))) float f32x4;

__device__ __forceinline__ float wave_sum(float v) {
  #pragma unroll
  for (int m = 1; m < 64; m <<= 1) v += __shfl_xor(v, m, 64);
  return v;
}

__device__ __forceinline__ u16 f2bf(float f) {
  u32 u = __float_as_uint(f);
  u += 0x7FFFu + ((u >> 16) & 1u);   // RNE
  return (u16)(u >> 16);
}
__device__ __forceinline__ float bf2f(u16 h) { return __uint_as_float(((u32)h) << 16); }
__device__ __forceinline__ u32 pk2(u16 a, u16 b) { return (u32)a | ((u32)b << 16); }

// ---------------- cls row ----------------
__global__ __launch_bounds__(256) void cls_kernel(const float* __restrict__ ct,
                                                  const float* __restrict__ pos,
                                                  float* __restrict__ t) {
  int b = blockIdx.x, d = threadIdx.x;
  t[((size_t)b * S) * D + d] = ct[d] + pos[d];
}

// ---------------- patch embed ----------------
__global__ __launch_bounds__(256) void patch_kernel(const float* __restrict__ x,
                                                    const float* __restrict__ pw,
                                                    const float* __restrict__ pb,
                                                    const float* __restrict__ pos,
                                                    float* __restrict__ t) {
  int n  = blockIdx.x & 255;
  int hb = (blockIdx.x >> 8) * 64;
  int pi = n >> 4, pj = n & 15;
  int lane = threadIdx.x & 63, w = threadIdx.x >> 6;
  int r = lane >> 2, c0 = (lane & 3) * 4;
  float4 p4[8];
  #pragma unroll
  for (int b = 0; b < 8; ++b)
    p4[b] = *(const float4*)&x[((size_t)b * 256 + pi * 16 + r) * 256 + pj * 16 + c0];

  for (int h = hb + w; h < hb + 64; h += 4) {
    const float4 w4 = *(const float4*)&pw[((size_t)h * 256 + n) * 256 + lane * 4];
    float part[8];
    #pragma unroll
    for (int b = 0; b < 8; ++b)
      part[b] = fmaf(p4[b].x, w4.x, fmaf(p4[b].y, w4.y, fmaf(p4[b].z, w4.z, p4[b].w * w4.w)));
    #pragma unroll
    for (int m = 1; m < 64; m <<= 1) {
      #pragma unroll
      for (int b = 0; b < 8; ++b) part[b] += __shfl_xor(part[b], m, 64);
    }
    if (lane < 8) {
      float addend = pb[h * 256 + n] + pos[(1 + h) * 256 + n];
      t[((size_t)lane * S + 1 + h) * D + n] = part[lane] + addend;
    }
  }
}

// ---------------- layernorm: one wave per row of 256 ----------------
__global__ __launch_bounds__(256) void ln_kernel(const float* __restrict__ in,
                                                 float* __restrict__ out,
                                                 const float* __restrict__ g,
                                                 const float* __restrict__ b,
                                                 int nrows) {
  int wid = threadIdx.x >> 6, lane = threadIdx.x & 63;
  int row = blockIdx.x * 4 + wid;
  if (row >= nrows) return;
  const float* p = in + (size_t)row * D;
  float4 v = *(const float4*)&p[lane * 4];
  float s = wave_sum(v.x + v.y + v.z + v.w);
  float mu = s * (1.0f / 256.0f);
  float dx = v.x - mu, dy = v.y - mu, dz = v.z - mu, dw = v.w - mu;
  float q = wave_sum(dx * dx + dy * dy + dz * dz + dw * dw);
  float rs = 1.0f / sqrtf(q * (1.0f / 256.0f) + 1e-5f);
  float4 gv = *(const float4*)&g[lane * 4];
  float4 bv = *(const float4*)&b[lane * 4];
  float4 o;
  o.x = dx * rs * gv.x + bv.x;
  o.y = dy * rs * gv.y + bv.y;
  o.z = dz * rs * gv.z + bv.z;
  o.w = dw * rs * gv.w + bv.w;
  *(float4*)&out[(size_t)row * D + lane * 4] = o;
}

// ---------------- weight conversion kernels ----------------
__global__ __launch_bounds__(256) void conv_copy3(const float* __restrict__ wq,
                                                  const float* __restrict__ wk,
                                                  const float* __restrict__ wv,
                                                  u16* __restrict__ W) {
  int wsel = blockIdx.x >> 6, tile = blockIdx.x & 63;
  const float* src = wsel == 0 ? wq : wsel == 1 ? wk : wv;
  u16* oh = W + wsel * 131072;
  u16* ol = oh + 65536;
  int r0 = (tile >> 3) * 32, c0 = (tile & 7) * 32;
  int tr = threadIdx.x >> 3, tc = (threadIdx.x & 7) * 4;
  const float4 f = *(const float4*)(src + (size_t)(r0 + tr) * 256 + c0 + tc);
  u16 h0 = f2bf(f.x), h1 = f2bf(f.y), h2 = f2bf(f.z), h3 = f2bf(f.w);
  u16 l0 = f2bf(f.x - bf2f(h0)), l1 = f2bf(f.y - bf2f(h1));
  u16 l2 = f2bf(f.z - bf2f(h2)), l3 = f2bf(f.w - bf2f(h3));
  size_t o = (size_t)(r0 + tr) * 256 + c0 + tc;
  *(uint2*)(oh + o) = make_uint2(pk2(h0, h1), pk2(h2, h3));
  *(uint2*)(ol + o) = make_uint2(pk2(l0, l1), pk2(l2, l3));
}

__global__ __launch_bounds__(256) void conv_trans(const float* __restrict__ src,
                                                  u16* __restrict__ oh,
                                                  u16* __restrict__ ol,
                                                  int R, int Cc) {
  __shared__ float lt[32][33];
  int tpc = Cc >> 5;
  int r0 = (blockIdx.x / tpc) * 32, c0 = (blockIdx.x % tpc) * 32;
  int tr = threadIdx.x >> 3, tc = (threadIdx.x & 7) * 4;
  float4 f = *(const float4*)(src + (size_t)(r0 + tr) * Cc + c0 + tc);
  lt[tr][tc + 0] = f.x; lt[tr][tc + 1] = f.y; lt[tr][tc + 2] = f.z; lt[tr][tc + 3] = f.w;
  __syncthreads();
  float a = lt[tc + 0][tr], b = lt[tc + 1][tr], c = lt[tc + 2][tr], d = lt[tc + 3][tr];
  u16 h0 = f2bf(a), h1 = f2bf(b), h2 = f2bf(c), h3 = f2bf(d);
  u16 l0 = f2bf(a - bf2f(h0)), l1 = f2bf(b - bf2f(h1));
  u16 l2 = f2bf(c - bf2f(h2)), l3 = f2bf(d - bf2f(h3));
  size_t o = (size_t)(c0 + tr) * R + r0 + tc;
  *(uint2*)(oh + o) = make_uint2(pk2(h0, h1), pk2(h2, h3));
  *(uint2*)(ol + o) = make_uint2(pk2(l0, l1), pk2(l2, l3));
}

// ---------------- MFMA split-bf16 GEMM ----------------
template<int AMODE, int HASBIAS, int RES, int GELU, int OUTBF>
__device__ __forceinline__ void gemm_core(const float* __restrict__ A32,
                                          const u16* __restrict__ A16,
                                          const u16* __restrict__ Bh,
                                          const u16* __restrict__ Bl,
                                          const float* __restrict__ bias,
                                          const float* __restrict__ res,
                                          float* __restrict__ Cf,
                                          u16* __restrict__ C16,
                                          int M, int N, int K, int row0, int col0) {
  __shared__ __align__(16) u16 sAh[4096];
  __shared__ __align__(16) u16 sAl[AMODE == 0 ? 4096 : 8];
  __shared__ __align__(16) u16 sBh[4096];
  __shared__ __align__(16) u16 sBl[4096];
  const int tid = threadIdx.x;
  const int lane = tid & 63;
  const int w = tid >> 6, wm = w >> 1, wn = w & 1;
  const int fr = lane & 15, g = lane >> 4;
  const int sr = tid >> 2, sc = tid & 3;
  int arow = row0 + sr; if (arow > M - 1) arow = M - 1;
  const u32 off0 = (u32)(sr * 128) + ((u32)((2 * sc)     ^ (sr & 7)) << 4);
  const u32 off1 = (u32)(sr * 128) + ((u32)((2 * sc + 1) ^ (sr & 7)) << 4);
  const float* ap32 = nullptr; const u16* ap16 = nullptr;
  if (AMODE == 0) ap32 = A32 + (size_t)arow * K + sc * 16;
  else            ap16 = A16 + (size_t)arow * K + sc * 16;
  const u16* bhp = Bh + (size_t)(col0 + sr) * K + sc * 16;
  const u16* blp = Bl + (size_t)(col0 + sr) * K + sc * 16;

  f32x4 acc[2][2], ac2[2][2];
  #pragma unroll
  for (int i = 0; i < 2; ++i)
    #pragma unroll
    for (int j = 0; j < 2; ++j) { acc[i][j] = (f32x4){0,0,0,0}; ac2[i][j] = (f32x4){0,0,0,0}; }

  for (int k0 = 0; k0 < K; k0 += 64) {
    uint4 wAh0, wAh1, wAl0, wAl1;
    if (AMODE == 0) {
      float fv[16];
      #pragma unroll
      for (int i = 0; i < 4; ++i) {
        float4 f4 = *(const float4*)(ap32 + k0 + i * 4);
        fv[i*4+0] = f4.x; fv[i*4+1] = f4.y; fv[i*4+2] = f4.z; fv[i*4+3] = f4.w;
      }
      u16 hh[16], ll[16];
      #pragma unroll
      for (int i = 0; i < 16; ++i) { u16 h = f2bf(fv[i]); hh[i] = h; ll[i] = f2bf(fv[i] - bf2f(h)); }
      wAh0 = make_uint4(pk2(hh[0],hh[1]), pk2(hh[2],hh[3]), pk2(hh[4],hh[5]), pk2(hh[6],hh[7]));
      wAh1 = make_uint4(pk2(hh[8],hh[9]), pk2(hh[10],hh[11]), pk2(hh[12],hh[13]), pk2(hh[14],hh[15]));
      wAl0 = make_uint4(pk2(ll[0],ll[1]), pk2(ll[2],ll[3]), pk2(ll[4],ll[5]), pk2(ll[6],ll[7]));
      wAl1 = make_uint4(pk2(ll[8],ll[9]), pk2(ll[10],ll[11]), pk2(ll[12],ll[13]), pk2(ll[14],ll[15]));
    } else {
      wAh0 = *(const uint4*)(ap16 + k0);
      wAh1 = *(const uint4*)(ap16 + k0 + 8);
      wAl0 = wAh0; wAl1 = wAh1; // unused
    }
    uint4 wBh0 = *(const uint4*)(bhp + k0);
    uint4 wBh1 = *(const uint4*)(bhp + k0 + 8);
    uint4 wBl0 = *(const uint4*)(blp + k0);
    uint4 wBl1 = *(const uint4*)(blp + k0 + 8);
    __syncthreads();
    *(uint4*)((char*)sAh + off0) = wAh0;
    *(uint4*)((char*)sAh + off1) = wAh1;
    if (AMODE == 0) {
      *(uint4*)((char*)sAl + off0) = wAl0;
      *(uint4*)((char*)sAl + off1) = wAl1;
    }
    *(uint4*)((char*)sBh + off0) = wBh0;
    *(uint4*)((char*)sBh + off1) = wBh1;
    *(uint4*)((char*)sBl + off0) = wBl0;
    *(uint4*)((char*)sBl + off1) = wBl1;
    __syncthreads();
    #pragma unroll
    for (int ks = 0; ks < 2; ++ks) {
      bshort8 ah[2], al[2], bh2[2], bl2[2];
      #pragma unroll
      for (int f = 0; f < 2; ++f) {
        int rA = wm * 32 + f * 16 + fr;
        u32 oa = (u32)(rA * 128) + ((u32)((ks * 4 + g) ^ (rA & 7)) << 4);
        ah[f] = *(const bshort8*)((const char*)sAh + oa);
        if (AMODE == 0) al[f] = *(const bshort8*)((const char*)sAl + oa);
        int rB = wn * 32 + f * 16 + fr;
        u32 ob = (u32)(rB * 128) + ((u32)((ks * 4 + g) ^ (rB & 7)) << 4);
        bh2[f] = *(const bshort8*)((const char*)sBh + ob);
        bl2[f] = *(const bshort8*)((const char*)sBl + ob);
      }
      #pragma unroll
      for (int fi = 0; fi < 2; ++fi)
        #pragma unroll
        for (int fj = 0; fj < 2; ++fj) {
          acc[fi][fj] = __builtin_amdgcn_mfma_f32_16x16x32_bf16(ah[fi], bh2[fj], acc[fi][fj], 0, 0, 0);
          ac2[fi][fj] = __builtin_amdgcn_mfma_f32_16x16x32_bf16(ah[fi], bl2[fj], ac2[fi][fj], 0, 0, 0);
          if (AMODE == 0)
            ac2[fi][fj] = __builtin_amdgcn_mfma_f32_16x16x32_bf16(al[fi], bh2[fj], ac2[fi][fj], 0, 0, 0);
        }
    }
  }
  #pragma unroll
  for (int fi = 0; fi < 2; ++fi) {
    #pragma unroll
    for (int fj = 0; fj < 2; ++fj) {
      int col = col0 + wn * 32 + fj * 16 + fr;
      int rbase = row0 + wm * 32 + fi * 16 + g * 4;
      #pragma unroll
      for (int r = 0; r < 4; ++r) {
        int row = rbase + r;
        if (row < M) {
          float v = acc[fi][fj][r] + ac2[fi][fj][r];
          if (HASBIAS) v += bias[col];
          if (GELU) v = 0.5f * v * (1.0f + erff(v * 0.70710678118654752440f));
          if (RES)  v += res[(size_t)row * N + col];
          if (OUTBF) C16[(size_t)row * N + col] = f2bf(v);
          else       Cf[(size_t)row * N + col] = v;
        }
      }
    }
  }
}

template<int AMODE, int HASBIAS, int RES, int GELU, int OUTBF>
__global__ __launch_bounds__(256) void gemm_k(const float* __restrict__ A32,
                                              const u16* __restrict__ A16,
                                              const u16* __restrict__ Bh,
                                              const u16* __restrict__ Bl,
                                              const float* __restrict__ bias,
                                              const float* __restrict__ res,
                                              float* __restrict__ Cf,
                                              u16* __restrict__ C16,
                                              int M, int N, int K) {
  gemm_core<AMODE, HASBIAS, RES, GELU, OUTBF>(A32, A16, Bh, Bl, bias, res, Cf, C16,
                                              M, N, K, blockIdx.y * 64, blockIdx.x * 64);
}

__global__ __launch_bounds__(256) void qkv_kernel(const float* __restrict__ xn,
                                                  const u16* __restrict__ W,
                                                  float* __restrict__ q,
                                                  float* __restrict__ k,
                                                  float* __restrict__ v) {
  int z = blockIdx.z;
  const u16* Bh = W + z * 131072;
  const u16* Bl = Bh + 65536;
  float* C = z == 0 ? q : z == 1 ? k : v;
  gemm_core<0, 0, 0, 0, 0>(xn, nullptr, Bh, Bl, nullptr, nullptr, C, nullptr,
                           M_ROWS, 256, 256, blockIdx.y * 64, blockIdx.x * 64);
}

// ---------------- attention (d_head = 1) ----------------
// block = (h, b); thread tid owns output row s=tid (0..255); row 256 cooperative.
__global__ __launch_bounds__(256) void attn_kernel(const float* __restrict__ Q,
                                                   const float* __restrict__ Kb,
                                                   const float* __restrict__ Vb,
                                                   float* __restrict__ O) {
  __shared__ __align__(16) float ks[S + 3], vs[S + 3];
  __shared__ float red[16];
  int h = blockIdx.x, b = blockIdx.y;
  size_t base = ((size_t)b * S) * D + h;
  int tid = threadIdx.x;
  int wid = tid >> 6, lane = tid & 63;
  for (int s = tid; s < S; s += 256) {
    ks[s] = Kb[base + (size_t)s * D];
    vs[s] = Vb[base + (size_t)s * D];
  }
  __syncthreads();
  float lmax = -1e30f, lmin = 1e30f;
  for (int s = tid; s < S; s += 256) {
    float kv = ks[s];
    lmax = fmaxf(lmax, kv); lmin = fminf(lmin, kv);
  }
  #pragma unroll
  for (int m = 1; m < 64; m <<= 1) {
    lmax = fmaxf(lmax, __shfl_xor(lmax, m, 64));
    lmin = fminf(lmin, __shfl_xor(lmin, m, 64));
  }
  if (lane == 0) { red[wid] = lmax; red[4 + wid] = lmin; }
  __syncthreads();
  float kmax = fmaxf(fmaxf(red[0], red[1]), fmaxf(red[2], red[3]));
  float kmin = fminf(fminf(red[4], red[5]), fminf(red[6], red[7]));

  const float L2E = 1.4426950408889634f;
  float qv = Q[base + (size_t)tid * D];
  float mm = qv >= 0.0f ? qv * kmax : qv * kmin;
  float ql = qv * L2E, nml = -mm * L2E;
  float den0 = 0, den1 = 0, den2 = 0, den3 = 0;
  float num0 = 0, num1 = 0, num2 = 0, num3 = 0;
  #pragma unroll 2
  for (int u = 0; u < 256; u += 8) {
    float4 k0 = *(const float4*)&ks[u];
    float4 k1 = *(const float4*)&ks[u + 4];
    float4 v0 = *(const float4*)&vs[u];
    float4 v1 = *(const float4*)&vs[u + 4];
    float e0 = exp2f(fmaf(ql, k0.x, nml));
    float e1 = exp2f(fmaf(ql, k0.y, nml));
    float e2 = exp2f(fmaf(ql, k0.z, nml));
    float e3 = exp2f(fmaf(ql, k0.w, nml));
    float e4 = exp2f(fmaf(ql, k1.x, nml));
    float e5 = exp2f(fmaf(ql, k1.y, nml));
    float e6 = exp2f(fmaf(ql, k1.z, nml));
    float e7 = exp2f(fmaf(ql, k1.w, nml));
    den0 += e0; num0 = fmaf(e0, v0.x, num0);
    den1 += e1; num1 = fmaf(e1, v0.y, num1);
    den2 += e2; num2 = fmaf(e2, v0.z, num2);
    den3 += e3; num3 = fmaf(e3, v0.w, num3);
    den0 += e4; num0 = fmaf(e4, v1.x, num0);
    den1 += e5; num1 = fmaf(e5, v1.y, num1);
    den2 += e6; num2 = fmaf(e6, v1.z, num2);
    den3 += e7; num3 = fmaf(e7, v1.w, num3);
  }
  {
    float e = exp2f(fmaf(ql, ks[256], nml));
    den0 += e; num0 = fmaf(e, vs[256], num0);
  }
  float den = (den0 + den1) + (den2 + den3);
  float num = (num0 + num1) + (num2 + num3);
  O[base + (size_t)tid * D] = num / den;

  // row 256, cooperative across the block
  float qv2 = Q[base + (size_t)256 * D];
  float mm2 = qv2 >= 0.0f ? qv2 * kmax : qv2 * kmin;
  float ql2 = qv2 * L2E, nml2 = -mm2 * L2E;
  float e = exp2f(fmaf(ql2, ks[tid], nml2));
  float dp = e, np = e * vs[tid];
  if (tid == 0) {
    float e2 = exp2f(fmaf(ql2, ks[256], nml2));
    dp += e2; np = fmaf(e2, vs[256], np);
  }
  dp = wave_sum(dp); np = wave_sum(np);
  if (lane == 0) { red[8 + wid] = dp; red[12 + wid] = np; }
  __syncthreads();
  if (tid == 0) {
    float dd = (red[8] + red[9]) + (red[10] + red[11]);
    float nn = (red[12] + red[13]) + (red[14] + red[15]);
    O[base + (size_t)256 * D] = nn / dd;
  }
}

// ---------------- head: logits + softmax, 1024 threads ----------------
__global__ __launch_bounds__(1024) void head_kernel(const float* __restrict__ t,
                                                    const float* __restrict__ hw,
                                                    const float* __restrict__ hb,
                                                    float* __restrict__ out) {
  __shared__ float trow[D];
  __shared__ float red[16];
  int b = blockIdx.x, tid = threadIdx.x;
  if (tid < D) trow[tid] = t[((size_t)b * S) * D + tid];
  __syncthreads();
  float acc = 0.0f;
  int n = tid;
  if (n < NCLS) {
    float a0 = 0, a1 = 0, a2 = 0, a3 = 0;
    #pragma unroll 4
    for (int d = 0; d < D; d += 4) {
      a0 = fmaf(trow[d + 0], hw[(size_t)(d + 0) * NCLS + n], a0);
      a1 = fmaf(trow[d + 1], hw[(size_t)(d + 1) * NCLS + n], a1);
      a2 = fmaf(trow[d + 2], hw[(size_t)(d + 2) * NCLS + n], a2);
      a3 = fmaf(trow[d + 3], hw[(size_t)(d + 3) * NCLS + n], a3);
    }
    acc = hb[n] + ((a0 + a1) + (a2 + a3));
  }
  float m = (n < NCLS) ? acc : -1e30f;
  #pragma unroll
  for (int s = 1; s < 64; s <<= 1) m = fmaxf(m, __shfl_xor(m, s, 64));
  int wid = tid >> 6, lane = tid & 63;
  if (lane == 0) red[wid] = m;
  __syncthreads();
  if (tid == 0) {
    float mm = red[0];
    #pragma unroll
    for (int i = 1; i < 16; ++i) mm = fmaxf(mm, red[i]);
    red[0] = mm;
  }
  __syncthreads();
  float gmax = red[0];
  float e = (n < NCLS) ? expf(acc - gmax) : 0.0f;
  float ss = e;
  #pragma unroll
  for (int s = 1; s < 64; s <<= 1) ss += __shfl_xor(ss, s, 64);
  __syncthreads();
  if (lane == 0) red[wid] = ss;
  __syncthreads();
  if (tid == 0) {
    float t2 = 0.0f;
    #pragma unroll
    for (int i = 0; i < 16; ++i) t2 += red[i];
    red[0] = t2;
  }
  __syncthreads();
  if (n < NCLS) out[(size_t)b * NCLS + n] = e / red[0];
}

// ---------------- launch ----------------
extern "C" void kernel_launch(void* const* d_in, const int* in_sizes, int n_in,
                              void* d_out, int out_size, void* d_ws, size_t ws_size,
                              hipStream_t stream) {
  const float* x        = (const float*)d_in[0];
  const float* class_tk = (const float*)d_in[1];
  const float* pos_emb  = (const float*)d_in[2];
  const float* patch_w  = (const float*)d_in[3];
  const float* patch_b  = (const float*)d_in[4];
  const float* wq       = (const float*)d_in[5];
  const float* wk       = (const float*)d_in[6];
  const float* wv       = (const float*)d_in[7];
  const float* proj_w   = (const float*)d_in[8];
  const float* proj_b   = (const float*)d_in[9];
  const float* mlp_w1   = (const float*)d_in[10];
  const float* mlp_b1   = (const float*)d_in[11];
  const float* mlp_w2   = (const float*)d_in[12];
  const float* mlp_b2   = (const float*)d_in[13];
  const float* ln1_g    = (const float*)d_in[14];
  const float* ln1_b    = (const float*)d_in[15];
  const float* ln2_g    = (const float*)d_in[16];
  const float* ln2_b    = (const float*)d_in[17];
  const float* head_w   = (const float*)d_in[18];
  const float* head_b   = (const float*)d_in[19];
  float* out = (float*)d_out;

  float* ws = (float*)d_ws;
  const size_t NTOK = (size_t)M_ROWS * D;   // 526336
  float* t  = ws;
  float* xn = ws + NTOK;
  float* q  = ws + 2 * NTOK;
  float* kk = ws + 3 * NTOK;
  float* v  = ws + 4 * NTOK;
  float* o  = ws + 5 * NTOK;
  u16* Wqkv = (u16*)(ws + 5 * NTOK);   // 6*65536 u16
  u16* W1   = (u16*)(ws + 2 * NTOK);   // 2*262144 u16
  u16* Wpj  = (u16*)(ws + 4 * NTOK);   // 2*65536 u16
  u16* H1   = (u16*)(ws + 3 * NTOK);   // 2056*1024 u16
  u16* W2   = (u16*)(ws + 1 * NTOK);   // 2*262144 u16

  conv_copy3<<<192, 256, 0, stream>>>(wq, wk, wv, Wqkv);
  cls_kernel<<<Bsz, 256, 0, stream>>>(class_tk, pos_emb, t);
  patch_kernel<<<1024, 256, 0, stream>>>(x, patch_w, patch_b, pos_emb, t);
  ln_kernel<<<(M_ROWS + 3) / 4, 256, 0, stream>>>(t, xn, ln1_g, ln1_b, M_ROWS);

  qkv_kernel<<<dim3(4, 33, 3), 256, 0, stream>>>(xn, Wqkv, q, kk, v);

  attn_kernel<<<dim3(256, Bsz), 256, 0, stream>>>(q, kk, v, o);

  conv_trans<<<64, 256, 0, stream>>>(proj_w, Wpj, Wpj + 65536, 256, 256);
  conv_trans<<<256, 256, 0, stream>>>(mlp_w1, W1, W1 + 262144, 256, 1024);

  gemm_k<0, 1, 1, 0, 0><<<dim3(4, 33), 256, 0, stream>>>(
      o, nullptr, Wpj, Wpj + 65536, proj_b, t, t, nullptr, M_ROWS, 256, 256);

  ln_kernel<<<(M_ROWS + 3) / 4, 256, 0, stream>>>(t, xn, ln2_g, ln2_b, M_ROWS);

  gemm_k<0, 1, 0, 1, 1><<<dim3(16, 33), 256, 0, stream>>>(
      xn, nullptr, W1, W1 + 262144, mlp_b1, nullptr, nullptr, H1, M_ROWS, MLP, 256);

  conv_trans<<<256, 256, 0, stream>>>(mlp_w2, W2, W2 + 262144, 1024, 256);

  gemm_k<1, 1, 1, 0, 0><<<dim3(4, 33), 256, 0, stream>>>(
      nullptr, H1, W2, W2 + 262144, mlp_b2, t, t, nullptr, M_ROWS, 256, MLP);

  head_kernel<<<Bsz, 1024, 0, stream>>>(t, head_w, head_b, out);
}

// Round 4
// 148.890 us; speedup vs baseline: 1.8002x; 1.1269x over previous
//
#include <hip/hip_runtime.h>
#include <math.h>

// ---------------- constants ----------------
#define Bsz   8
#define CHUNK 16
#define D     256      // d_model = num_heads = num_patches = 256
#define S     257      // seq len
#define MLP   1024
#define NCLS  1000
#define M_ROWS (Bsz * S)   // 2056

typedef unsigned int u32;
typedef unsigned short u16;
typedef __attribute__((ext_vector_type(8))) short bshort8;
typedef __attribute__((ext_vector_type(4))) float f32x4;

__device__ __forceinline__ float wave_sum(float v) {
  #pragma unroll
  for (int m = 1; m < 64; m <<= 1) v += __shfl_xor(v, m, 64);
  return v;
}

__device__ __forceinline__ u16 f2bf(float f) {
  u32 u = __float_as_uint(f);
  u += 0x7FFFu + ((u >> 16) & 1u);   // RNE
  return (u16)(u >> 16);
}
__device__ __forceinline__ float bf2f(u16 h) { return __uint_as_float(((u32)h) << 16); }
__device__ __forceinline__ u32 pk2(u16 a, u16 b) { return (u32)a | ((u32)b << 16); }

// ---------------- cls row ----------------
__global__ __launch_bounds__(256) void cls_kernel(const float* __restrict__ ct,
                                                  const float* __restrict__ pos,
                                                  float* __restrict__ t) {
  int b = blockIdx.x, d = threadIdx.x;
  t[((size_t)b * S) * D + d] = ct[d] + pos[d];
}

// ---------------- patch embed as MFMA mini-GEMM ----------------
// per n: out[b(8) x h(256)] = p_n[8x256] . pw_n[256h x 256i]^T
// block = (h-tile of 64, n); 4 waves, each owns one 16x16 C-frag (rows 0-7 valid).
__global__ __launch_bounds__(256) void patch_gemm(const float* __restrict__ x,
                                                  const float* __restrict__ pw,
                                                  const float* __restrict__ pb,
                                                  const float* __restrict__ pos,
                                                  float* __restrict__ t) {
  __shared__ __align__(16) u16 sAh[4096], sAl[4096], sBh[4096], sBl[4096];
  const int n = blockIdx.y;
  const int col0 = blockIdx.x * 64;
  const int pi = n >> 4, pj = n & 15;
  const int tid = threadIdx.x, lane = tid & 63;
  const int w = tid >> 6;
  const int fr = lane & 15, g = lane >> 4;
  const int sr = tid >> 2, sc = tid & 3;
  const int arow = sr > 7 ? 7 : sr;   // M=8, clamp (dup row 7, L1-hit)
  const u32 off0 = (u32)(sr * 128) + ((u32)((2 * sc)     ^ (sr & 7)) << 4);
  const u32 off1 = (u32)(sr * 128) + ((u32)((2 * sc + 1) ^ (sr & 7)) << 4);
  // A[b][k]: k=r*16+c -> x[b*65536 + (pi*16+r)*256 + pj*16 + c]
  const float* ap32 = x + (size_t)arow * 65536 + (size_t)(pi * 16) * 256 + pj * 16;
  const float* bp32 = pw + (size_t)(col0 + sr) * 65536 + (size_t)n * 256 + sc * 16;

  f32x4 acc = {0, 0, 0, 0}, ac2 = {0, 0, 0, 0};

  for (int k0 = 0; k0 < 256; k0 += 64) {
    // A: 16 floats (contiguous 64B: one (r, c0..15) row-chunk)
    const float* asrc = ap32 + (size_t)((k0 >> 4) + sc) * 256;
    float fa[16], fb[16];
    #pragma unroll
    for (int i = 0; i < 4; ++i) {
      float4 f4 = *(const float4*)(asrc + i * 4);
      fa[i*4+0] = f4.x; fa[i*4+1] = f4.y; fa[i*4+2] = f4.z; fa[i*4+3] = f4.w;
      float4 g4 = *(const float4*)(bp32 + k0 + i * 4);
      fb[i*4+0] = g4.x; fb[i*4+1] = g4.y; fb[i*4+2] = g4.z; fb[i*4+3] = g4.w;
    }
    u16 ah16[16], al16[16], bh16[16], bl16[16];
    #pragma unroll
    for (int i = 0; i < 16; ++i) {
      u16 h = f2bf(fa[i]); ah16[i] = h; al16[i] = f2bf(fa[i] - bf2f(h));
      u16 hb = f2bf(fb[i]); bh16[i] = hb; bl16[i] = f2bf(fb[i] - bf2f(hb));
    }
    __syncthreads();
    *(uint4*)((char*)sAh + off0) = make_uint4(pk2(ah16[0],ah16[1]), pk2(ah16[2],ah16[3]), pk2(ah16[4],ah16[5]), pk2(ah16[6],ah16[7]));
    *(uint4*)((char*)sAh + off1) = make_uint4(pk2(ah16[8],ah16[9]), pk2(ah16[10],ah16[11]), pk2(ah16[12],ah16[13]), pk2(ah16[14],ah16[15]));
    *(uint4*)((char*)sAl + off0) = make_uint4(pk2(al16[0],al16[1]), pk2(al16[2],al16[3]), pk2(al16[4],al16[5]), pk2(al16[6],al16[7]));
    *(uint4*)((char*)sAl + off1) = make_uint4(pk2(al16[8],al16[9]), pk2(al16[10],al16[11]), pk2(al16[12],al16[13]), pk2(al16[14],al16[15]));
    *(uint4*)((char*)sBh + off0) = make_uint4(pk2(bh16[0],bh16[1]), pk2(bh16[2],bh16[3]), pk2(bh16[4],bh16[5]), pk2(bh16[6],bh16[7]));
    *(uint4*)((char*)sBh + off1) = make_uint4(pk2(bh16[8],bh16[9]), pk2(bh16[10],bh16[11]), pk2(bh16[12],bh16[13]), pk2(bh16[14],bh16[15]));
    *(uint4*)((char*)sBl + off0) = make_uint4(pk2(bl16[0],bl16[1]), pk2(bl16[2],bl16[3]), pk2(bl16[4],bl16[5]), pk2(bl16[6],bl16[7]));
    *(uint4*)((char*)sBl + off1) = make_uint4(pk2(bl16[8],bl16[9]), pk2(bl16[10],bl16[11]), pk2(bl16[12],bl16[13]), pk2(bl16[14],bl16[15]));
    __syncthreads();
    #pragma unroll
    for (int ks = 0; ks < 2; ++ks) {
      int rA = fr;
      u32 oa = (u32)(rA * 128) + ((u32)((ks * 4 + g) ^ (rA & 7)) << 4);
      bshort8 ah = *(const bshort8*)((const char*)sAh + oa);
      bshort8 al = *(const bshort8*)((const char*)sAl + oa);
      int rB = w * 16 + fr;
      u32 ob = (u32)(rB * 128) + ((u32)((ks * 4 + g) ^ (rB & 7)) << 4);
      bshort8 bh = *(const bshort8*)((const char*)sBh + ob);
      bshort8 bl = *(const bshort8*)((const char*)sBl + ob);
      acc = __builtin_amdgcn_mfma_f32_16x16x32_bf16(ah, bh, acc, 0, 0, 0);
      ac2 = __builtin_amdgcn_mfma_f32_16x16x32_bf16(ah, bl, ac2, 0, 0, 0);
      ac2 = __builtin_amdgcn_mfma_f32_16x16x32_bf16(al, bh, ac2, 0, 0, 0);
    }
  }
  if (g < 2) {
    int h = col0 + w * 16 + fr;
    float addend = pb[h * 256 + n] + pos[(1 + h) * 256 + n];
    #pragma unroll
    for (int r = 0; r < 4; ++r) {
      int b = g * 4 + r;
      t[((size_t)b * S + 1 + h) * D + n] = acc[r] + ac2[r] + addend;
    }
  }
}

// ---------------- layernorm: one wave per row of 256 ----------------
__global__ __launch_bounds__(256) void ln_kernel(const float* __restrict__ in,
                                                 float* __restrict__ out,
                                                 const float* __restrict__ g,
                                                 const float* __restrict__ b,
                                                 int nrows) {
  int wid = threadIdx.x >> 6, lane = threadIdx.x & 63;
  int row = blockIdx.x * 4 + wid;
  if (row >= nrows) return;
  const float* p = in + (size_t)row * D;
  float4 v = *(const float4*)&p[lane * 4];
  float s = wave_sum(v.x + v.y + v.z + v.w);
  float mu = s * (1.0f / 256.0f);
  float dx = v.x - mu, dy = v.y - mu, dz = v.z - mu, dw = v.w - mu;
  float q = wave_sum(dx * dx + dy * dy + dz * dz + dw * dw);
  float rs = 1.0f / sqrtf(q * (1.0f / 256.0f) + 1e-5f);
  float4 gv = *(const float4*)&g[lane * 4];
  float4 bv = *(const float4*)&b[lane * 4];
  float4 o;
  o.x = dx * rs * gv.x + bv.x;
  o.y = dy * rs * gv.y + bv.y;
  o.z = dz * rs * gv.z + bv.z;
  o.w = dw * rs * gv.w + bv.w;
  *(float4*)&out[(size_t)row * D + lane * 4] = o;
}

// ---------------- weight conversion kernels ----------------
__global__ __launch_bounds__(256) void conv_copy3(const float* __restrict__ wq,
                                                  const float* __restrict__ wk,
                                                  const float* __restrict__ wv,
                                                  u16* __restrict__ W) {
  int wsel = blockIdx.x >> 6, tile = blockIdx.x & 63;
  const float* src = wsel == 0 ? wq : wsel == 1 ? wk : wv;
  u16* oh = W + wsel * 131072;
  u16* ol = oh + 65536;
  int r0 = (tile >> 3) * 32, c0 = (tile & 7) * 32;
  int tr = threadIdx.x >> 3, tc = (threadIdx.x & 7) * 4;
  const float4 f = *(const float4*)(src + (size_t)(r0 + tr) * 256 + c0 + tc);
  u16 h0 = f2bf(f.x), h1 = f2bf(f.y), h2 = f2bf(f.z), h3 = f2bf(f.w);
  u16 l0 = f2bf(f.x - bf2f(h0)), l1 = f2bf(f.y - bf2f(h1));
  u16 l2 = f2bf(f.z - bf2f(h2)), l3 = f2bf(f.w - bf2f(h3));
  size_t o = (size_t)(r0 + tr) * 256 + c0 + tc;
  *(uint2*)(oh + o) = make_uint2(pk2(h0, h1), pk2(h2, h3));
  *(uint2*)(ol + o) = make_uint2(pk2(l0, l1), pk2(l2, l3));
}

__global__ __launch_bounds__(256) void conv_trans(const float* __restrict__ src,
                                                  u16* __restrict__ oh,
                                                  u16* __restrict__ ol,
                                                  int R, int Cc) {
  __shared__ float lt[32][33];
  int tpc = Cc >> 5;
  int r0 = (blockIdx.x / tpc) * 32, c0 = (blockIdx.x % tpc) * 32;
  int tr = threadIdx.x >> 3, tc = (threadIdx.x & 7) * 4;
  float4 f = *(const float4*)(src + (size_t)(r0 + tr) * Cc + c0 + tc);
  lt[tr][tc + 0] = f.x; lt[tr][tc + 1] = f.y; lt[tr][tc + 2] = f.z; lt[tr][tc + 3] = f.w;
  __syncthreads();
  float a = lt[tc + 0][tr], b = lt[tc + 1][tr], c = lt[tc + 2][tr], d = lt[tc + 3][tr];
  u16 h0 = f2bf(a), h1 = f2bf(b), h2 = f2bf(c), h3 = f2bf(d);
  u16 l0 = f2bf(a - bf2f(h0)), l1 = f2bf(b - bf2f(h1));
  u16 l2 = f2bf(c - bf2f(h2)), l3 = f2bf(d - bf2f(h3));
  size_t o = (size_t)(c0 + tr) * R + r0 + tc;
  *(uint2*)(oh + o) = make_uint2(pk2(h0, h1), pk2(h2, h3));
  *(uint2*)(ol + o) = make_uint2(pk2(l0, l1), pk2(l2, l3));
}

// ---------------- MFMA split-bf16 GEMM ----------------
// OUTT=1: write C transposed as [b][col][s] with row = b*257+s (for QKV->attn).
template<int AMODE, int HASBIAS, int RES, int GELU, int OUTBF, int OUTT>
__device__ __forceinline__ void gemm_core(const float* __restrict__ A32,
                                          const u16* __restrict__ A16,
                                          const u16* __restrict__ Bh,
                                          const u16* __restrict__ Bl,
                                          const float* __restrict__ bias,
                                          const float* __restrict__ res,
                                          float* __restrict__ Cf,
                                          u16* __restrict__ C16,
                                          int M, int N, int K, int row0, int col0) {
  __shared__ __align__(16) u16 sAh[4096];
  __shared__ __align__(16) u16 sAl[AMODE == 0 ? 4096 : 8];
  __shared__ __align__(16) u16 sBh[4096];
  __shared__ __align__(16) u16 sBl[4096];
  const int tid = threadIdx.x;
  const int lane = tid & 63;
  const int w = tid >> 6, wm = w >> 1, wn = w & 1;
  const int fr = lane & 15, g = lane >> 4;
  const int sr = tid >> 2, sc = tid & 3;
  int arow = row0 + sr; if (arow > M - 1) arow = M - 1;
  const u32 off0 = (u32)(sr * 128) + ((u32)((2 * sc)     ^ (sr & 7)) << 4);
  const u32 off1 = (u32)(sr * 128) + ((u32)((2 * sc + 1) ^ (sr & 7)) << 4);
  const float* ap32 = nullptr; const u16* ap16 = nullptr;
  if (AMODE == 0) ap32 = A32 + (size_t)arow * K + sc * 16;
  else            ap16 = A16 + (size_t)arow * K + sc * 16;
  const u16* bhp = Bh + (size_t)(col0 + sr) * K + sc * 16;
  const u16* blp = Bl + (size_t)(col0 + sr) * K + sc * 16;

  f32x4 acc[2][2], ac2[2][2];
  #pragma unroll
  for (int i = 0; i < 2; ++i)
    #pragma unroll
    for (int j = 0; j < 2; ++j) { acc[i][j] = (f32x4){0,0,0,0}; ac2[i][j] = (f32x4){0,0,0,0}; }

  for (int k0 = 0; k0 < K; k0 += 64) {
    uint4 wAh0, wAh1, wAl0, wAl1;
    if (AMODE == 0) {
      float fv[16];
      #pragma unroll
      for (int i = 0; i < 4; ++i) {
        float4 f4 = *(const float4*)(ap32 + k0 + i * 4);
        fv[i*4+0] = f4.x; fv[i*4+1] = f4.y; fv[i*4+2] = f4.z; fv[i*4+3] = f4.w;
      }
      u16 hh[16], ll[16];
      #pragma unroll
      for (int i = 0; i < 16; ++i) { u16 h = f2bf(fv[i]); hh[i] = h; ll[i] = f2bf(fv[i] - bf2f(h)); }
      wAh0 = make_uint4(pk2(hh[0],hh[1]), pk2(hh[2],hh[3]), pk2(hh[4],hh[5]), pk2(hh[6],hh[7]));
      wAh1 = make_uint4(pk2(hh[8],hh[9]), pk2(hh[10],hh[11]), pk2(hh[12],hh[13]), pk2(hh[14],hh[15]));
      wAl0 = make_uint4(pk2(ll[0],ll[1]), pk2(ll[2],ll[3]), pk2(ll[4],ll[5]), pk2(ll[6],ll[7]));
      wAl1 = make_uint4(pk2(ll[8],ll[9]), pk2(ll[10],ll[11]), pk2(ll[12],ll[13]), pk2(ll[14],ll[15]));
    } else {
      wAh0 = *(const uint4*)(ap16 + k0);
      wAh1 = *(const uint4*)(ap16 + k0 + 8);
      wAl0 = wAh0; wAl1 = wAh1; // unused
    }
    uint4 wBh0 = *(const uint4*)(bhp + k0);
    uint4 wBh1 = *(const uint4*)(bhp + k0 + 8);
    uint4 wBl0 = *(const uint4*)(blp + k0);
    uint4 wBl1 = *(const uint4*)(blp + k0 + 8);
    __syncthreads();
    *(uint4*)((char*)sAh + off0) = wAh0;
    *(uint4*)((char*)sAh + off1) = wAh1;
    if (AMODE == 0) {
      *(uint4*)((char*)sAl + off0) = wAl0;
      *(uint4*)((char*)sAl + off1) = wAl1;
    }
    *(uint4*)((char*)sBh + off0) = wBh0;
    *(uint4*)((char*)sBh + off1) = wBh1;
    *(uint4*)((char*)sBl + off0) = wBl0;
    *(uint4*)((char*)sBl + off1) = wBl1;
    __syncthreads();
    #pragma unroll
    for (int ks = 0; ks < 2; ++ks) {
      bshort8 ah[2], al[2], bh2[2], bl2[2];
      #pragma unroll
      for (int f = 0; f < 2; ++f) {
        int rA = wm * 32 + f * 16 + fr;
        u32 oa = (u32)(rA * 128) + ((u32)((ks * 4 + g) ^ (rA & 7)) << 4);
        ah[f] = *(const bshort8*)((const char*)sAh + oa);
        if (AMODE == 0) al[f] = *(const bshort8*)((const char*)sAl + oa);
        int rB = wn * 32 + f * 16 + fr;
        u32 ob = (u32)(rB * 128) + ((u32)((ks * 4 + g) ^ (rB & 7)) << 4);
        bh2[f] = *(const bshort8*)((const char*)sBh + ob);
        bl2[f] = *(const bshort8*)((const char*)sBl + ob);
      }
      #pragma unroll
      for (int fi = 0; fi < 2; ++fi)
        #pragma unroll
        for (int fj = 0; fj < 2; ++fj) {
          acc[fi][fj] = __builtin_amdgcn_mfma_f32_16x16x32_bf16(ah[fi], bh2[fj], acc[fi][fj], 0, 0, 0);
          ac2[fi][fj] = __builtin_amdgcn_mfma_f32_16x16x32_bf16(ah[fi], bl2[fj], ac2[fi][fj], 0, 0, 0);
          if (AMODE == 0)
            ac2[fi][fj] = __builtin_amdgcn_mfma_f32_16x16x32_bf16(al[fi], bh2[fj], ac2[fi][fj], 0, 0, 0);
        }
    }
  }
  #pragma unroll
  for (int fi = 0; fi < 2; ++fi) {
    #pragma unroll
    for (int fj = 0; fj < 2; ++fj) {
      int col = col0 + wn * 32 + fj * 16 + fr;
      int rbase = row0 + wm * 32 + fi * 16 + g * 4;
      #pragma unroll
      for (int r = 0; r < 4; ++r) {
        int row = rbase + r;
        if (row < M) {
          float v = acc[fi][fj][r] + ac2[fi][fj][r];
          if (HASBIAS) v += bias[col];
          if (GELU) v = 0.5f * v * (1.0f + erff(v * 0.70710678118654752440f));
          if (RES)  v += res[(size_t)row * N + col];
          if (OUTT) {
            u32 bq = (u32)row / 257u;
            u32 sq = (u32)row - bq * 257u;
            Cf[((size_t)bq * 256 + col) * 257 + sq] = v;
          } else if (OUTBF) {
            C16[(size_t)row * N + col] = f2bf(v);
          } else {
            Cf[(size_t)row * N + col] = v;
          }
        }
      }
    }
  }
}

template<int AMODE, int HASBIAS, int RES, int GELU, int OUTBF>
__global__ __launch_bounds__(256) void gemm_k(const float* __restrict__ A32,
                                              const u16* __restrict__ A16,
                                              const u16* __restrict__ Bh,
                                              const u16* __restrict__ Bl,
                                              const float* __restrict__ bias,
                                              const float* __restrict__ res,
                                              float* __restrict__ Cf,
                                              u16* __restrict__ C16,
                                              int M, int N, int K) {
  gemm_core<AMODE, HASBIAS, RES, GELU, OUTBF, 0>(A32, A16, Bh, Bl, bias, res, Cf, C16,
                                                 M, N, K, blockIdx.y * 64, blockIdx.x * 64);
}

// QKV with transposed output [b][h][s]
__global__ __launch_bounds__(256) void qkv_kernel(const float* __restrict__ xn,
                                                  const u16* __restrict__ W,
                                                  float* __restrict__ q,
                                                  float* __restrict__ k,
                                                  float* __restrict__ v) {
  int z = blockIdx.z;
  const u16* Bh = W + z * 131072;
  const u16* Bl = Bh + 65536;
  float* C = z == 0 ? q : z == 1 ? k : v;
  gemm_core<0, 0, 0, 0, 0, 1>(xn, nullptr, Bh, Bl, nullptr, nullptr, C, nullptr,
                              M_ROWS, 256, 256, blockIdx.y * 64, blockIdx.x * 64);
}

// ---------------- attention (d_head = 1), Q/K/V transposed [b][h][s] ----------------
__global__ __launch_bounds__(256) void attn_kernel(const float* __restrict__ Q,
                                                   const float* __restrict__ Kb,
                                                   const float* __restrict__ Vb,
                                                   float* __restrict__ O) {
  __shared__ __align__(16) float ks[S + 3], vs[S + 3];
  __shared__ float red[16];
  int h = blockIdx.x, b = blockIdx.y;
  size_t rowbase = ((size_t)b * 256 + h) * 257;
  int tid = threadIdx.x;
  int wid = tid >> 6, lane = tid & 63;
  for (int s = tid; s < S; s += 256) {
    ks[s] = Kb[rowbase + s];
    vs[s] = Vb[rowbase + s];
  }
  __syncthreads();
  float lmax = -1e30f, lmin = 1e30f;
  for (int s = tid; s < S; s += 256) {
    float kv = ks[s];
    lmax = fmaxf(lmax, kv); lmin = fminf(lmin, kv);
  }
  #pragma unroll
  for (int m = 1; m < 64; m <<= 1) {
    lmax = fmaxf(lmax, __shfl_xor(lmax, m, 64));
    lmin = fminf(lmin, __shfl_xor(lmin, m, 64));
  }
  if (lane == 0) { red[wid] = lmax; red[4 + wid] = lmin; }
  __syncthreads();
  float kmax = fmaxf(fmaxf(red[0], red[1]), fmaxf(red[2], red[3]));
  float kmin = fminf(fminf(red[4], red[5]), fminf(red[6], red[7]));

  const float L2E = 1.4426950408889634f;
  float qv = Q[rowbase + tid];
  float mm = qv >= 0.0f ? qv * kmax : qv * kmin;
  float ql = qv * L2E, nml = -mm * L2E;
  float den0 = 0, den1 = 0, den2 = 0, den3 = 0;
  float num0 = 0, num1 = 0, num2 = 0, num3 = 0;
  #pragma unroll 2
  for (int u = 0; u < 256; u += 8) {
    float4 k0 = *(const float4*)&ks[u];
    float4 k1 = *(const float4*)&ks[u + 4];
    float4 v0 = *(const float4*)&vs[u];
    float4 v1 = *(const float4*)&vs[u + 4];
    float e0 = exp2f(fmaf(ql, k0.x, nml));
    float e1 = exp2f(fmaf(ql, k0.y, nml));
    float e2 = exp2f(fmaf(ql, k0.z, nml));
    float e3 = exp2f(fmaf(ql, k0.w, nml));
    float e4 = exp2f(fmaf(ql, k1.x, nml));
    float e5 = exp2f(fmaf(ql, k1.y, nml));
    float e6 = exp2f(fmaf(ql, k1.z, nml));
    float e7 = exp2f(fmaf(ql, k1.w, nml));
    den0 += e0; num0 = fmaf(e0, v0.x, num0);
    den1 += e1; num1 = fmaf(e1, v0.y, num1);
    den2 += e2; num2 = fmaf(e2, v0.z, num2);
    den3 += e3; num3 = fmaf(e3, v0.w, num3);
    den0 += e4; num0 = fmaf(e4, v1.x, num0);
    den1 += e5; num1 = fmaf(e5, v1.y, num1);
    den2 += e6; num2 = fmaf(e6, v1.z, num2);
    den3 += e7; num3 = fmaf(e7, v1.w, num3);
  }
  {
    float e = exp2f(fmaf(ql, ks[256], nml));
    den0 += e; num0 = fmaf(e, vs[256], num0);
  }
  float den = (den0 + den1) + (den2 + den3);
  float num = (num0 + num1) + (num2 + num3);
  O[((size_t)b * S + tid) * D + h] = num / den;

  // row 256, cooperative across the block
  float qv2 = Q[rowbase + 256];
  float mm2 = qv2 >= 0.0f ? qv2 * kmax : qv2 * kmin;
  float ql2 = qv2 * L2E, nml2 = -mm2 * L2E;
  float e = exp2f(fmaf(ql2, ks[tid], nml2));
  float dp = e, np = e * vs[tid];
  if (tid == 0) {
    float e2 = exp2f(fmaf(ql2, ks[256], nml2));
    dp += e2; np = fmaf(e2, vs[256], np);
  }
  dp = wave_sum(dp); np = wave_sum(np);
  if (lane == 0) { red[8 + wid] = dp; red[12 + wid] = np; }
  __syncthreads();
  if (tid == 0) {
    float dd = (red[8] + red[9]) + (red[10] + red[11]);
    float nn = (red[12] + red[13]) + (red[14] + red[15]);
    O[((size_t)b * S + 256) * D + h] = nn / dd;
  }
}

// ---------------- head: logits + softmax, 1024 threads ----------------
__global__ __launch_bounds__(1024) void head_kernel(const float* __restrict__ t,
                                                    const float* __restrict__ hw,
                                                    const float* __restrict__ hb,
                                                    float* __restrict__ out) {
  __shared__ float trow[D];
  __shared__ float red[16];
  int b = blockIdx.x, tid = threadIdx.x;
  if (tid < D) trow[tid] = t[((size_t)b * S) * D + tid];
  __syncthreads();
  float acc = 0.0f;
  int n = tid;
  if (n < NCLS) {
    float a0 = 0, a1 = 0, a2 = 0, a3 = 0;
    #pragma unroll 4
    for (int d = 0; d < D; d += 4) {
      a0 = fmaf(trow[d + 0], hw[(size_t)(d + 0) * NCLS + n], a0);
      a1 = fmaf(trow[d + 1], hw[(size_t)(d + 1) * NCLS + n], a1);
      a2 = fmaf(trow[d + 2], hw[(size_t)(d + 2) * NCLS + n], a2);
      a3 = fmaf(trow[d + 3], hw[(size_t)(d + 3) * NCLS + n], a3);
    }
    acc = hb[n] + ((a0 + a1) + (a2 + a3));
  }
  float m = (n < NCLS) ? acc : -1e30f;
  #pragma unroll
  for (int s = 1; s < 64; s <<= 1) m = fmaxf(m, __shfl_xor(m, s, 64));
  int wid = tid >> 6, lane = tid & 63;
  if (lane == 0) red[wid] = m;
  __syncthreads();
  if (tid == 0) {
    float mm = red[0];
    #pragma unroll
    for (int i = 1; i < 16; ++i) mm = fmaxf(mm, red[i]);
    red[0] = mm;
  }
  __syncthreads();
  float gmax = red[0];
  float e = (n < NCLS) ? expf(acc - gmax) : 0.0f;
  float ss = e;
  #pragma unroll
  for (int s = 1; s < 64; s <<= 1) ss += __shfl_xor(ss, s, 64);
  __syncthreads();
  if (lane == 0) red[wid] = ss;
  __syncthreads();
  if (tid == 0) {
    float t2 = 0.0f;
    #pragma unroll
    for (int i = 0; i < 16; ++i) t2 += red[i];
    red[0] = t2;
  }
  __syncthreads();
  if (n < NCLS) out[(size_t)b * NCLS + n] = e / red[0];
}

// ---------------- launch ----------------
extern "C" void kernel_launch(void* const* d_in, const int* in_sizes, int n_in,
                              void* d_out, int out_size, void* d_ws, size_t ws_size,
                              hipStream_t stream) {
  const float* x        = (const float*)d_in[0];
  const float* class_tk = (const float*)d_in[1];
  const float* pos_emb  = (const float*)d_in[2];
  const float* patch_w  = (const float*)d_in[3];
  const float* patch_b  = (const float*)d_in[4];
  const float* wq       = (const float*)d_in[5];
  const float* wk       = (const float*)d_in[6];
  const float* wv       = (const float*)d_in[7];
  const float* proj_w   = (const float*)d_in[8];
  const float* proj_b   = (const float*)d_in[9];
  const float* mlp_w1   = (const float*)d_in[10];
  const float* mlp_b1   = (const float*)d_in[11];
  const float* mlp_w2   = (const float*)d_in[12];
  const float* mlp_b2   = (const float*)d_in[13];
  const float* ln1_g    = (const float*)d_in[14];
  const float* ln1_b    = (const float*)d_in[15];
  const float* ln2_g    = (const float*)d_in[16];
  const float* ln2_b    = (const float*)d_in[17];
  const float* head_w   = (const float*)d_in[18];
  const float* head_b   = (const float*)d_in[19];
  float* out = (float*)d_out;

  float* ws = (float*)d_ws;
  const size_t NTOK = (size_t)M_ROWS * D;   // 526336
  float* t  = ws;
  float* xn = ws + NTOK;
  float* q  = ws + 2 * NTOK;   // transposed [b][h][s]
  float* kk = ws + 3 * NTOK;   // transposed
  float* v  = ws + 4 * NTOK;   // transposed
  float* o  = ws + 5 * NTOK;   // row-major [b*S+s][h]
  u16* Wqkv = (u16*)(ws + 5 * NTOK);   // 6*65536 u16 (dead once attn writes o)
  u16* W1   = (u16*)(ws + 2 * NTOK);   // 2*262144 u16 (q dead after attn)
  u16* Wpj  = (u16*)(ws + 4 * NTOK);   // 2*65536 u16 (v dead after attn)
  u16* H1   = (u16*)(ws + 3 * NTOK);   // 2056*1024 u16
  u16* W2   = (u16*)(ws + 1 * NTOK);   // 2*262144 u16 (xn dead after mlp1)

  conv_copy3<<<192, 256, 0, stream>>>(wq, wk, wv, Wqkv);
  cls_kernel<<<Bsz, 256, 0, stream>>>(class_tk, pos_emb, t);
  patch_gemm<<<dim3(4, 256), 256, 0, stream>>>(x, patch_w, patch_b, pos_emb, t);
  ln_kernel<<<(M_ROWS + 3) / 4, 256, 0, stream>>>(t, xn, ln1_g, ln1_b, M_ROWS);

  qkv_kernel<<<dim3(4, 33, 3), 256, 0, stream>>>(xn, Wqkv, q, kk, v);

  attn_kernel<<<dim3(256, Bsz), 256, 0, stream>>>(q, kk, v, o);

  conv_trans<<<64, 256, 0, stream>>>(proj_w, Wpj, Wpj + 65536, 256, 256);
  conv_trans<<<256, 256, 0, stream>>>(mlp_w1, W1, W1 + 262144, 256, 1024);

  gemm_k<0, 1, 1, 0, 0><<<dim3(4, 33), 256, 0, stream>>>(
      o, nullptr, Wpj, Wpj + 65536, proj_b, t, t, nullptr, M_ROWS, 256, 256);

  ln_kernel<<<(M_ROWS + 3) / 4, 256, 0, stream>>>(t, xn, ln2_g, ln2_b, M_ROWS);

  gemm_k<0, 1, 0, 1, 1><<<dim3(16, 33), 256, 0, stream>>>(
      xn, nullptr, W1, W1 + 262144, mlp_b1, nullptr, nullptr, H1, M_ROWS, MLP, 256);

  conv_trans<<<256, 256, 0, stream>>>(mlp_w2, W2, W2 + 262144, 1024, 256);

  gemm_k<1, 1, 1, 0, 0><<<dim3(4, 33), 256, 0, stream>>>(
      nullptr, H1, W2, W2 + 262144, mlp_b2, t, t, nullptr, M_ROWS, 256, MLP);

  head_kernel<<<Bsz, 1024, 0, stream>>>(t, head_w, head_b, out);
}

// Round 5
// 126.001 us; speedup vs baseline: 2.1272x; 1.1817x over previous
//
#include <hip/hip_runtime.h>
#include <math.h>

// ---------------- constants ----------------
#define Bsz   8
#define CHUNK 16
#define D     256      // d_model = num_heads = num_patches = 256
#define S     257      // seq len
#define MLP   1024
#define NCLS  1000
#define M_ROWS (Bsz * S)   // 2056

typedef unsigned int u32;
typedef unsigned short u16;
typedef __attribute__((ext_vector_type(8))) short bshort8;
typedef __attribute__((ext_vector_type(4))) float f32x4;

__device__ __forceinline__ float wave_sum(float v) {
  #pragma unroll
  for (int m = 1; m < 64; m <<= 1) v += __shfl_xor(v, m, 64);
  return v;
}

__device__ __forceinline__ u16 f2bf(float f) {
  u32 u = __float_as_uint(f);
  u += 0x7FFFu + ((u >> 16) & 1u);   // RNE
  return (u16)(u >> 16);
}
__device__ __forceinline__ float bf2f(u16 h) { return __uint_as_float(((u32)h) << 16); }
__device__ __forceinline__ u32 pk2(u16 a, u16 b) { return (u32)a | ((u32)b << 16); }

// raw v_exp_f32 — args bounded in [-40, 0] here, no OCML guards needed
__device__ __forceinline__ float fexp2(float x) { return __builtin_amdgcn_exp2f(x); }

// ---------------- patch embed as MFMA mini-GEMM (cls row fused) ----------------
__global__ __launch_bounds__(256) void patch_gemm(const float* __restrict__ x,
                                                  const float* __restrict__ pw,
                                                  const float* __restrict__ pb,
                                                  const float* __restrict__ pos,
                                                  const float* __restrict__ ct,
                                                  float* __restrict__ t) {
  __shared__ __align__(16) u16 sAh[4096], sAl[4096], sBh[4096], sBl[4096];
  const int n = blockIdx.y;
  const int col0 = blockIdx.x * 64;
  const int pi = n >> 4, pj = n & 15;
  const int tid = threadIdx.x, lane = tid & 63;
  const int w = tid >> 6;
  const int fr = lane & 15, g = lane >> 4;
  const int sr = tid >> 2, sc = tid & 3;
  const int arow = sr > 7 ? 7 : sr;   // M=8, clamp (dup row 7, L1-hit)
  const u32 off0 = (u32)(sr * 128) + ((u32)((2 * sc)     ^ (sr & 7)) << 4);
  const u32 off1 = (u32)(sr * 128) + ((u32)((2 * sc + 1) ^ (sr & 7)) << 4);
  const float* ap32 = x + (size_t)arow * 65536 + (size_t)(pi * 16) * 256 + pj * 16;
  const float* bp32 = pw + (size_t)(col0 + sr) * 65536 + (size_t)n * 256 + sc * 16;

  // fused cls row: t[b,0,n] = ct[n] + pos[0,n]
  if (blockIdx.x == 0 && tid < 8)
    t[((size_t)tid * S) * D + n] = ct[n] + pos[n];

  f32x4 acc = {0, 0, 0, 0}, ac2 = {0, 0, 0, 0};

  for (int k0 = 0; k0 < 256; k0 += 64) {
    const float* asrc = ap32 + (size_t)((k0 >> 4) + sc) * 256;
    float fa[16], fb[16];
    #pragma unroll
    for (int i = 0; i < 4; ++i) {
      float4 f4 = *(const float4*)(asrc + i * 4);
      fa[i*4+0] = f4.x; fa[i*4+1] = f4.y; fa[i*4+2] = f4.z; fa[i*4+3] = f4.w;
      float4 g4 = *(const float4*)(bp32 + k0 + i * 4);
      fb[i*4+0] = g4.x; fb[i*4+1] = g4.y; fb[i*4+2] = g4.z; fb[i*4+3] = g4.w;
    }
    u16 ah16[16], al16[16], bh16[16], bl16[16];
    #pragma unroll
    for (int i = 0; i < 16; ++i) {
      u16 h = f2bf(fa[i]); ah16[i] = h; al16[i] = f2bf(fa[i] - bf2f(h));
      u16 hb = f2bf(fb[i]); bh16[i] = hb; bl16[i] = f2bf(fb[i] - bf2f(hb));
    }
    __syncthreads();
    *(uint4*)((char*)sAh + off0) = make_uint4(pk2(ah16[0],ah16[1]), pk2(ah16[2],ah16[3]), pk2(ah16[4],ah16[5]), pk2(ah16[6],ah16[7]));
    *(uint4*)((char*)sAh + off1) = make_uint4(pk2(ah16[8],ah16[9]), pk2(ah16[10],ah16[11]), pk2(ah16[12],ah16[13]), pk2(ah16[14],ah16[15]));
    *(uint4*)((char*)sAl + off0) = make_uint4(pk2(al16[0],al16[1]), pk2(al16[2],al16[3]), pk2(al16[4],al16[5]), pk2(al16[6],al16[7]));
    *(uint4*)((char*)sAl + off1) = make_uint4(pk2(al16[8],al16[9]), pk2(al16[10],al16[11]), pk2(al16[12],al16[13]), pk2(al16[14],al16[15]));
    *(uint4*)((char*)sBh + off0) = make_uint4(pk2(bh16[0],bh16[1]), pk2(bh16[2],bh16[3]), pk2(bh16[4],bh16[5]), pk2(bh16[6],bh16[7]));
    *(uint4*)((char*)sBh + off1) = make_uint4(pk2(bh16[8],bh16[9]), pk2(bh16[10],bh16[11]), pk2(bh16[12],bh16[13]), pk2(bh16[14],bh16[15]));
    *(uint4*)((char*)sBl + off0) = make_uint4(pk2(bl16[0],bl16[1]), pk2(bl16[2],bl16[3]), pk2(bl16[4],bl16[5]), pk2(bl16[6],bl16[7]));
    *(uint4*)((char*)sBl + off1) = make_uint4(pk2(bl16[8],bl16[9]), pk2(bl16[10],bl16[11]), pk2(bl16[12],bl16[13]), pk2(bl16[14],bl16[15]));
    __syncthreads();
    #pragma unroll
    for (int ks = 0; ks < 2; ++ks) {
      int rA = fr;
      u32 oa = (u32)(rA * 128) + ((u32)((ks * 4 + g) ^ (rA & 7)) << 4);
      bshort8 ah = *(const bshort8*)((const char*)sAh + oa);
      bshort8 al = *(const bshort8*)((const char*)sAl + oa);
      int rB = w * 16 + fr;
      u32 ob = (u32)(rB * 128) + ((u32)((ks * 4 + g) ^ (rB & 7)) << 4);
      bshort8 bh = *(const bshort8*)((const char*)sBh + ob);
      bshort8 bl = *(const bshort8*)((const char*)sBl + ob);
      acc = __builtin_amdgcn_mfma_f32_16x16x32_bf16(ah, bh, acc, 0, 0, 0);
      ac2 = __builtin_amdgcn_mfma_f32_16x16x32_bf16(ah, bl, ac2, 0, 0, 0);
      ac2 = __builtin_amdgcn_mfma_f32_16x16x32_bf16(al, bh, ac2, 0, 0, 0);
    }
  }
  if (g < 2) {
    int h = col0 + w * 16 + fr;
    float addend = pb[h * 256 + n] + pos[(1 + h) * 256 + n];
    #pragma unroll
    for (int r = 0; r < 4; ++r) {
      int b = g * 4 + r;
      t[((size_t)b * S + 1 + h) * D + n] = acc[r] + ac2[r] + addend;
    }
  }
}

// ---------------- layernorm: one wave per row of 256 ----------------
__global__ __launch_bounds__(256) void ln_kernel(const float* __restrict__ in,
                                                 float* __restrict__ out,
                                                 const float* __restrict__ g,
                                                 const float* __restrict__ b,
                                                 int nrows) {
  int wid = threadIdx.x >> 6, lane = threadIdx.x & 63;
  int row = blockIdx.x * 4 + wid;
  if (row >= nrows) return;
  const float* p = in + (size_t)row * D;
  float4 v = *(const float4*)&p[lane * 4];
  float s = wave_sum(v.x + v.y + v.z + v.w);
  float mu = s * (1.0f / 256.0f);
  float dx = v.x - mu, dy = v.y - mu, dz = v.z - mu, dw = v.w - mu;
  float q = wave_sum(dx * dx + dy * dy + dz * dz + dw * dw);
  float rs = 1.0f / sqrtf(q * (1.0f / 256.0f) + 1e-5f);
  float4 gv = *(const float4*)&g[lane * 4];
  float4 bv = *(const float4*)&b[lane * 4];
  float4 o;
  o.x = dx * rs * gv.x + bv.x;
  o.y = dy * rs * gv.y + bv.y;
  o.z = dz * rs * gv.z + bv.z;
  o.w = dw * rs * gv.w + bv.w;
  *(float4*)&out[(size_t)row * D + lane * 4] = o;
}

// ---------------- weight conversion bodies ----------------
__device__ __forceinline__ void conv_copy3_body(int blk, int tid,
                                                const float* __restrict__ wq,
                                                const float* __restrict__ wk,
                                                const float* __restrict__ wv,
                                                u16* __restrict__ W) {
  int wsel = blk >> 6, tile = blk & 63;
  const float* src = wsel == 0 ? wq : wsel == 1 ? wk : wv;
  u16* oh = W + wsel * 131072;
  u16* ol = oh + 65536;
  int r0 = (tile >> 3) * 32, c0 = (tile & 7) * 32;
  int tr = tid >> 3, tc = (tid & 7) * 4;
  const float4 f = *(const float4*)(src + (size_t)(r0 + tr) * 256 + c0 + tc);
  u16 h0 = f2bf(f.x), h1 = f2bf(f.y), h2 = f2bf(f.z), h3 = f2bf(f.w);
  u16 l0 = f2bf(f.x - bf2f(h0)), l1 = f2bf(f.y - bf2f(h1));
  u16 l2 = f2bf(f.z - bf2f(h2)), l3 = f2bf(f.w - bf2f(h3));
  size_t o = (size_t)(r0 + tr) * 256 + c0 + tc;
  *(uint2*)(oh + o) = make_uint2(pk2(h0, h1), pk2(h2, h3));
  *(uint2*)(ol + o) = make_uint2(pk2(l0, l1), pk2(l2, l3));
}

__device__ __forceinline__ void conv_trans_body(int blk, int tid,
                                                const float* __restrict__ src,
                                                u16* __restrict__ oh,
                                                u16* __restrict__ ol,
                                                int R, int Cc) {
  __shared__ float lt[32][33];
  int tpc = Cc >> 5;
  int r0 = (blk / tpc) * 32, c0 = (blk % tpc) * 32;
  int tr = tid >> 3, tc = (tid & 7) * 4;
  float4 f = *(const float4*)(src + (size_t)(r0 + tr) * Cc + c0 + tc);
  lt[tr][tc + 0] = f.x; lt[tr][tc + 1] = f.y; lt[tr][tc + 2] = f.z; lt[tr][tc + 3] = f.w;
  __syncthreads();
  float a = lt[tc + 0][tr], b = lt[tc + 1][tr], c = lt[tc + 2][tr], d = lt[tc + 3][tr];
  u16 h0 = f2bf(a), h1 = f2bf(b), h2 = f2bf(c), h3 = f2bf(d);
  u16 l0 = f2bf(a - bf2f(h0)), l1 = f2bf(b - bf2f(h1));
  u16 l2 = f2bf(c - bf2f(h2)), l3 = f2bf(d - bf2f(h3));
  size_t o = (size_t)(c0 + tr) * R + r0 + tc;
  *(uint2*)(oh + o) = make_uint2(pk2(h0, h1), pk2(h2, h3));
  *(uint2*)(ol + o) = make_uint2(pk2(l0, l1), pk2(l2, l3));
}

__global__ __launch_bounds__(256) void conv_copy3(const float* __restrict__ wq,
                                                  const float* __restrict__ wk,
                                                  const float* __restrict__ wv,
                                                  u16* __restrict__ W) {
  conv_copy3_body(blockIdx.x, threadIdx.x, wq, wk, wv, W);
}

__global__ __launch_bounds__(256) void conv_trans(const float* __restrict__ src,
                                                  u16* __restrict__ oh,
                                                  u16* __restrict__ ol,
                                                  int R, int Cc) {
  conv_trans_body(blockIdx.x, threadIdx.x, src, oh, ol, R, Cc);
}

// one launch for all weight conversions: [0,192) copy3 | [192,256) proj | [256,512) w1 | [512,768) w2
__global__ __launch_bounds__(256) void conv_all(const float* __restrict__ wq,
                                                const float* __restrict__ wk,
                                                const float* __restrict__ wv,
                                                const float* __restrict__ proj_w,
                                                const float* __restrict__ mlp_w1,
                                                const float* __restrict__ mlp_w2,
                                                u16* __restrict__ Wqkv,
                                                u16* __restrict__ Wpj,
                                                u16* __restrict__ W1,
                                                u16* __restrict__ W2) {
  int blk = blockIdx.x, tid = threadIdx.x;
  if (blk < 192)      conv_copy3_body(blk, tid, wq, wk, wv, Wqkv);
  else if (blk < 256) conv_trans_body(blk - 192, tid, proj_w, Wpj, Wpj + 65536, 256, 256);
  else if (blk < 512) conv_trans_body(blk - 256, tid, mlp_w1, W1, W1 + 262144, 256, 1024);
  else                conv_trans_body(blk - 512, tid, mlp_w2, W2, W2 + 262144, 1024, 256);
}

// ---------------- MFMA split-bf16 GEMM ----------------
template<int AMODE, int HASBIAS, int RES, int GELU, int OUTBF, int OUTT>
__device__ __forceinline__ void gemm_core(const float* __restrict__ A32,
                                          const u16* __restrict__ A16,
                                          const u16* __restrict__ Bh,
                                          const u16* __restrict__ Bl,
                                          const float* __restrict__ bias,
                                          const float* __restrict__ res,
                                          float* __restrict__ Cf,
                                          u16* __restrict__ C16,
                                          int M, int N, int K, int row0, int col0) {
  __shared__ __align__(16) u16 sAh[4096];
  __shared__ __align__(16) u16 sAl[AMODE == 0 ? 4096 : 8];
  __shared__ __align__(16) u16 sBh[4096];
  __shared__ __align__(16) u16 sBl[4096];
  const int tid = threadIdx.x;
  const int lane = tid & 63;
  const int w = tid >> 6, wm = w >> 1, wn = w & 1;
  const int fr = lane & 15, g = lane >> 4;
  const int sr = tid >> 2, sc = tid & 3;
  int arow = row0 + sr; if (arow > M - 1) arow = M - 1;
  const u32 off0 = (u32)(sr * 128) + ((u32)((2 * sc)     ^ (sr & 7)) << 4);
  const u32 off1 = (u32)(sr * 128) + ((u32)((2 * sc + 1) ^ (sr & 7)) << 4);
  const float* ap32 = nullptr; const u16* ap16 = nullptr;
  if (AMODE == 0) ap32 = A32 + (size_t)arow * K + sc * 16;
  else            ap16 = A16 + (size_t)arow * K + sc * 16;
  const u16* bhp = Bh + (size_t)(col0 + sr) * K + sc * 16;
  const u16* blp = Bl + (size_t)(col0 + sr) * K + sc * 16;

  f32x4 acc[2][2], ac2[2][2];
  #pragma unroll
  for (int i = 0; i < 2; ++i)
    #pragma unroll
    for (int j = 0; j < 2; ++j) { acc[i][j] = (f32x4){0,0,0,0}; ac2[i][j] = (f32x4){0,0,0,0}; }

  for (int k0 = 0; k0 < K; k0 += 64) {
    uint4 wAh0, wAh1, wAl0, wAl1;
    if (AMODE == 0) {
      float fv[16];
      #pragma unroll
      for (int i = 0; i < 4; ++i) {
        float4 f4 = *(const float4*)(ap32 + k0 + i * 4);
        fv[i*4+0] = f4.x; fv[i*4+1] = f4.y; fv[i*4+2] = f4.z; fv[i*4+3] = f4.w;
      }
      u16 hh[16], ll[16];
      #pragma unroll
      for (int i = 0; i < 16; ++i) { u16 h = f2bf(fv[i]); hh[i] = h; ll[i] = f2bf(fv[i] - bf2f(h)); }
      wAh0 = make_uint4(pk2(hh[0],hh[1]), pk2(hh[2],hh[3]), pk2(hh[4],hh[5]), pk2(hh[6],hh[7]));
      wAh1 = make_uint4(pk2(hh[8],hh[9]), pk2(hh[10],hh[11]), pk2(hh[12],hh[13]), pk2(hh[14],hh[15]));
      wAl0 = make_uint4(pk2(ll[0],ll[1]), pk2(ll[2],ll[3]), pk2(ll[4],ll[5]), pk2(ll[6],ll[7]));
      wAl1 = make_uint4(pk2(ll[8],ll[9]), pk2(ll[10],ll[11]), pk2(ll[12],ll[13]), pk2(ll[14],ll[15]));
    } else {
      wAh0 = *(const uint4*)(ap16 + k0);
      wAh1 = *(const uint4*)(ap16 + k0 + 8);
      wAl0 = wAh0; wAl1 = wAh1; // unused
    }
    uint4 wBh0 = *(const uint4*)(bhp + k0);
    uint4 wBh1 = *(const uint4*)(bhp + k0 + 8);
    uint4 wBl0 = *(const uint4*)(blp + k0);
    uint4 wBl1 = *(const uint4*)(blp + k0 + 8);
    __syncthreads();
    *(uint4*)((char*)sAh + off0) = wAh0;
    *(uint4*)((char*)sAh + off1) = wAh1;
    if (AMODE == 0) {
      *(uint4*)((char*)sAl + off0) = wAl0;
      *(uint4*)((char*)sAl + off1) = wAl1;
    }
    *(uint4*)((char*)sBh + off0) = wBh0;
    *(uint4*)((char*)sBh + off1) = wBh1;
    *(uint4*)((char*)sBl + off0) = wBl0;
    *(uint4*)((char*)sBl + off1) = wBl1;
    __syncthreads();
    #pragma unroll
    for (int ks = 0; ks < 2; ++ks) {
      bshort8 ah[2], al[2], bh2[2], bl2[2];
      #pragma unroll
      for (int f = 0; f < 2; ++f) {
        int rA = wm * 32 + f * 16 + fr;
        u32 oa = (u32)(rA * 128) + ((u32)((ks * 4 + g) ^ (rA & 7)) << 4);
        ah[f] = *(const bshort8*)((const char*)sAh + oa);
        if (AMODE == 0) al[f] = *(const bshort8*)((const char*)sAl + oa);
        int rB = wn * 32 + f * 16 + fr;
        u32 ob = (u32)(rB * 128) + ((u32)((ks * 4 + g) ^ (rB & 7)) << 4);
        bh2[f] = *(const bshort8*)((const char*)sBh + ob);
        bl2[f] = *(const bshort8*)((const char*)sBl + ob);
      }
      #pragma unroll
      for (int fi = 0; fi < 2; ++fi)
        #pragma unroll
        for (int fj = 0; fj < 2; ++fj) {
          acc[fi][fj] = __builtin_amdgcn_mfma_f32_16x16x32_bf16(ah[fi], bh2[fj], acc[fi][fj], 0, 0, 0);
          ac2[fi][fj] = __builtin_amdgcn_mfma_f32_16x16x32_bf16(ah[fi], bl2[fj], ac2[fi][fj], 0, 0, 0);
          if (AMODE == 0)
            ac2[fi][fj] = __builtin_amdgcn_mfma_f32_16x16x32_bf16(al[fi], bh2[fj], ac2[fi][fj], 0, 0, 0);
        }
    }
  }
  #pragma unroll
  for (int fi = 0; fi < 2; ++fi) {
    #pragma unroll
    for (int fj = 0; fj < 2; ++fj) {
      int col = col0 + wn * 32 + fj * 16 + fr;
      int rbase = row0 + wm * 32 + fi * 16 + g * 4;
      #pragma unroll
      for (int r = 0; r < 4; ++r) {
        int row = rbase + r;
        if (row < M) {
          float v = acc[fi][fj][r] + ac2[fi][fj][r];
          if (HASBIAS) v += bias[col];
          if (GELU) v = 0.5f * v * (1.0f + erff(v * 0.70710678118654752440f));
          if (RES)  v += res[(size_t)row * N + col];
          if (OUTT) {
            u32 bq = (u32)row / 257u;
            u32 sq = (u32)row - bq * 257u;
            Cf[((size_t)bq * 256 + col) * 257 + sq] = v;
          } else if (OUTBF) {
            C16[(size_t)row * N + col] = f2bf(v);
          } else {
            Cf[(size_t)row * N + col] = v;
          }
        }
      }
    }
  }
}

template<int AMODE, int HASBIAS, int RES, int GELU, int OUTBF>
__global__ __launch_bounds__(256) void gemm_k(const float* __restrict__ A32,
                                              const u16* __restrict__ A16,
                                              const u16* __restrict__ Bh,
                                              const u16* __restrict__ Bl,
                                              const float* __restrict__ bias,
                                              const float* __restrict__ res,
                                              float* __restrict__ Cf,
                                              u16* __restrict__ C16,
                                              int M, int N, int K) {
  gemm_core<AMODE, HASBIAS, RES, GELU, OUTBF, 0>(A32, A16, Bh, Bl, bias, res, Cf, C16,
                                                 M, N, K, blockIdx.y * 64, blockIdx.x * 64);
}

// QKV with transposed output [b][h][s]
__global__ __launch_bounds__(256) void qkv_kernel(const float* __restrict__ xn,
                                                  const u16* __restrict__ W,
                                                  float* __restrict__ q,
                                                  float* __restrict__ k,
                                                  float* __restrict__ v) {
  int z = blockIdx.z;
  const u16* Bh = W + z * 131072;
  const u16* Bl = Bh + 65536;
  float* C = z == 0 ? q : z == 1 ? k : v;
  gemm_core<0, 0, 0, 0, 0, 1>(xn, nullptr, Bh, Bl, nullptr, nullptr, C, nullptr,
                              M_ROWS, 256, 256, blockIdx.y * 64, blockIdx.x * 64);
}

// ---------------- attention (d_head = 1), Q/K/V transposed [b][h][s] ----------------
__global__ __launch_bounds__(256) void attn_kernel(const float* __restrict__ Q,
                                                   const float* __restrict__ Kb,
                                                   const float* __restrict__ Vb,
                                                   float* __restrict__ O) {
  __shared__ __align__(16) float ks[S + 3], vs[S + 3];
  __shared__ float red[16];
  int h = blockIdx.x, b = blockIdx.y;
  size_t rowbase = ((size_t)b * 256 + h) * 257;
  int tid = threadIdx.x;
  int wid = tid >> 6, lane = tid & 63;
  for (int s = tid; s < S; s += 256) {
    ks[s] = Kb[rowbase + s];
    vs[s] = Vb[rowbase + s];
  }
  __syncthreads();
  float lmax = -1e30f, lmin = 1e30f;
  for (int s = tid; s < S; s += 256) {
    float kv = ks[s];
    lmax = fmaxf(lmax, kv); lmin = fminf(lmin, kv);
  }
  #pragma unroll
  for (int m = 1; m < 64; m <<= 1) {
    lmax = fmaxf(lmax, __shfl_xor(lmax, m, 64));
    lmin = fminf(lmin, __shfl_xor(lmin, m, 64));
  }
  if (lane == 0) { red[wid] = lmax; red[4 + wid] = lmin; }
  __syncthreads();
  float kmax = fmaxf(fmaxf(red[0], red[1]), fmaxf(red[2], red[3]));
  float kmin = fminf(fminf(red[4], red[5]), fminf(red[6], red[7]));

  const float L2E = 1.4426950408889634f;
  float qv = Q[rowbase + tid];
  float mm = qv >= 0.0f ? qv * kmax : qv * kmin;
  float ql = qv * L2E, nml = -mm * L2E;
  float den0 = 0, den1 = 0, den2 = 0, den3 = 0;
  float num0 = 0, num1 = 0, num2 = 0, num3 = 0;
  #pragma unroll 2
  for (int u = 0; u < 256; u += 8) {
    float4 k0 = *(const float4*)&ks[u];
    float4 k1 = *(const float4*)&ks[u + 4];
    float4 v0 = *(const float4*)&vs[u];
    float4 v1 = *(const float4*)&vs[u + 4];
    float e0 = fexp2(fmaf(ql, k0.x, nml));
    float e1 = fexp2(fmaf(ql, k0.y, nml));
    float e2 = fexp2(fmaf(ql, k0.z, nml));
    float e3 = fexp2(fmaf(ql, k0.w, nml));
    float e4 = fexp2(fmaf(ql, k1.x, nml));
    float e5 = fexp2(fmaf(ql, k1.y, nml));
    float e6 = fexp2(fmaf(ql, k1.z, nml));
    float e7 = fexp2(fmaf(ql, k1.w, nml));
    den0 += e0; num0 = fmaf(e0, v0.x, num0);
    den1 += e1; num1 = fmaf(e1, v0.y, num1);
    den2 += e2; num2 = fmaf(e2, v0.z, num2);
    den3 += e3; num3 = fmaf(e3, v0.w, num3);
    den0 += e4; num0 = fmaf(e4, v1.x, num0);
    den1 += e5; num1 = fmaf(e5, v1.y, num1);
    den2 += e6; num2 = fmaf(e6, v1.z, num2);
    den3 += e7; num3 = fmaf(e7, v1.w, num3);
  }
  {
    float e = fexp2(fmaf(ql, ks[256], nml));
    den0 += e; num0 = fmaf(e, vs[256], num0);
  }
  float den = (den0 + den1) + (den2 + den3);
  float num = (num0 + num1) + (num2 + num3);
  O[((size_t)b * S + tid) * D + h] = num / den;

  // row 256, cooperative across the block
  float qv2 = Q[rowbase + 256];
  float mm2 = qv2 >= 0.0f ? qv2 * kmax : qv2 * kmin;
  float ql2 = qv2 * L2E, nml2 = -mm2 * L2E;
  float e = fexp2(fmaf(ql2, ks[tid], nml2));
  float dp = e, np = e * vs[tid];
  if (tid == 0) {
    float e2 = fexp2(fmaf(ql2, ks[256], nml2));
    dp += e2; np = fmaf(e2, vs[256], np);
  }
  dp = wave_sum(dp); np = wave_sum(np);
  if (lane == 0) { red[8 + wid] = dp; red[12 + wid] = np; }
  __syncthreads();
  if (tid == 0) {
    float dd = (red[8] + red[9]) + (red[10] + red[11]);
    float nn = (red[12] + red[13]) + (red[14] + red[15]);
    O[((size_t)b * S + 256) * D + h] = nn / dd;
  }
}

// ---------------- head: logits + softmax, 1024 threads ----------------
__global__ __launch_bounds__(1024) void head_kernel(const float* __restrict__ t,
                                                    const float* __restrict__ hw,
                                                    const float* __restrict__ hb,
                                                    float* __restrict__ out) {
  __shared__ float trow[D];
  __shared__ float red[16];
  int b = blockIdx.x, tid = threadIdx.x;
  if (tid < D) trow[tid] = t[((size_t)b * S) * D + tid];
  __syncthreads();
  float acc = 0.0f;
  int n = tid;
  if (n < NCLS) {
    float a0 = 0, a1 = 0, a2 = 0, a3 = 0;
    #pragma unroll 4
    for (int d = 0; d < D; d += 4) {
      a0 = fmaf(trow[d + 0], hw[(size_t)(d + 0) * NCLS + n], a0);
      a1 = fmaf(trow[d + 1], hw[(size_t)(d + 1) * NCLS + n], a1);
      a2 = fmaf(trow[d + 2], hw[(size_t)(d + 2) * NCLS + n], a2);
      a3 = fmaf(trow[d + 3], hw[(size_t)(d + 3) * NCLS + n], a3);
    }
    acc = hb[n] + ((a0 + a1) + (a2 + a3));
  }
  float m = (n < NCLS) ? acc : -1e30f;
  #pragma unroll
  for (int s = 1; s < 64; s <<= 1) m = fmaxf(m, __shfl_xor(m, s, 64));
  int wid = tid >> 6, lane = tid & 63;
  if (lane == 0) red[wid] = m;
  __syncthreads();
  if (tid == 0) {
    float mm = red[0];
    #pragma unroll
    for (int i = 1; i < 16; ++i) mm = fmaxf(mm, red[i]);
    red[0] = mm;
  }
  __syncthreads();
  float gmax = red[0];
  float e = (n < NCLS) ? expf(acc - gmax) : 0.0f;
  float ss = e;
  #pragma unroll
  for (int s = 1; s < 64; s <<= 1) ss += __shfl_xor(ss, s, 64);
  __syncthreads();
  if (lane == 0) red[wid] = ss;
  __syncthreads();
  if (tid == 0) {
    float t2 = 0.0f;
    #pragma unroll
    for (int i = 0; i < 16; ++i) t2 += red[i];
    red[0] = t2;
  }
  __syncthreads();
  if (n < NCLS) out[(size_t)b * NCLS + n] = e / red[0];
}

// ---------------- launch ----------------
extern "C" void kernel_launch(void* const* d_in, const int* in_sizes, int n_in,
                              void* d_out, int out_size, void* d_ws, size_t ws_size,
                              hipStream_t stream) {
  const float* x        = (const float*)d_in[0];
  const float* class_tk = (const float*)d_in[1];
  const float* pos_emb  = (const float*)d_in[2];
  const float* patch_w  = (const float*)d_in[3];
  const float* patch_b  = (const float*)d_in[4];
  const float* wq       = (const float*)d_in[5];
  const float* wk       = (const float*)d_in[6];
  const float* wv       = (const float*)d_in[7];
  const float* proj_w   = (const float*)d_in[8];
  const float* proj_b   = (const float*)d_in[9];
  const float* mlp_w1   = (const float*)d_in[10];
  const float* mlp_b1   = (const float*)d_in[11];
  const float* mlp_w2   = (const float*)d_in[12];
  const float* mlp_b2   = (const float*)d_in[13];
  const float* ln1_g    = (const float*)d_in[14];
  const float* ln1_b    = (const float*)d_in[15];
  const float* ln2_g    = (const float*)d_in[16];
  const float* ln2_b    = (const float*)d_in[17];
  const float* head_w   = (const float*)d_in[18];
  const float* head_b   = (const float*)d_in[19];
  float* out = (float*)d_out;

  float* ws = (float*)d_ws;
  const size_t NTOK = (size_t)M_ROWS * D;   // 526336
  float* t  = ws;
  float* xn = ws + NTOK;
  float* q  = ws + 2 * NTOK;   // transposed [b][h][s]
  float* kk = ws + 3 * NTOK;   // transposed
  float* v  = ws + 4 * NTOK;   // transposed
  float* o  = ws + 5 * NTOK;   // row-major [b*S+s][h]
  u16* H1;                     // 2056*1024 u16 = 4.2 MB
  u16 *Wqkv, *Wpj, *W1, *W2;

  // tail layout (all weights disjoint, single conversion launch) needs:
  // 6*NTOK*4 + (6+2)*65536*2 + 2*2*262144*2 = 15,728,640 B
  const size_t tail_need = 6 * NTOK * 4 + 8 * 65536 * 2 + 4 * 262144 * 2;
  bool tail = ws_size >= tail_need;
  if (tail) {
    u16* wbase = (u16*)(ws + 6 * NTOK);
    Wqkv = wbase;                  // 6*65536
    Wpj  = wbase + 6 * 65536;      // 2*65536
    W1   = wbase + 8 * 65536;      // 2*262144
    W2   = W1 + 2 * 262144;        // 2*262144
    H1   = (u16*)(ws + 2 * NTOK);  // q/k region, dead after attn
  } else {
    Wqkv = (u16*)(ws + 5 * NTOK);
    W1   = (u16*)(ws + 2 * NTOK);
    Wpj  = (u16*)(ws + 4 * NTOK);
    H1   = (u16*)(ws + 3 * NTOK);
    W2   = (u16*)(ws + 1 * NTOK);
  }

  if (tail) {
    conv_all<<<768, 256, 0, stream>>>(wq, wk, wv, proj_w, mlp_w1, mlp_w2, Wqkv, Wpj, W1, W2);
  } else {
    conv_copy3<<<192, 256, 0, stream>>>(wq, wk, wv, Wqkv);
  }

  patch_gemm<<<dim3(4, 256), 256, 0, stream>>>(x, patch_w, patch_b, pos_emb, class_tk, t);
  ln_kernel<<<(M_ROWS + 3) / 4, 256, 0, stream>>>(t, xn, ln1_g, ln1_b, M_ROWS);

  qkv_kernel<<<dim3(4, 33, 3), 256, 0, stream>>>(xn, Wqkv, q, kk, v);

  attn_kernel<<<dim3(256, Bsz), 256, 0, stream>>>(q, kk, v, o);

  if (!tail) {
    conv_trans<<<64, 256, 0, stream>>>(proj_w, Wpj, Wpj + 65536, 256, 256);
    conv_trans<<<256, 256, 0, stream>>>(mlp_w1, W1, W1 + 262144, 256, 1024);
  }

  gemm_k<0, 1, 1, 0, 0><<<dim3(4, 33), 256, 0, stream>>>(
      o, nullptr, Wpj, Wpj + 65536, proj_b, t, t, nullptr, M_ROWS, 256, 256);

  ln_kernel<<<(M_ROWS + 3) / 4, 256, 0, stream>>>(t, xn, ln2_g, ln2_b, M_ROWS);

  gemm_k<0, 1, 0, 1, 1><<<dim3(16, 33), 256, 0, stream>>>(
      xn, nullptr, W1, W1 + 262144, mlp_b1, nullptr, nullptr, H1, M_ROWS, MLP, 256);

  if (!tail) {
    conv_trans<<<256, 256, 0, stream>>>(mlp_w2, W2, W2 + 262144, 1024, 256);
  }

  gemm_k<1, 1, 1, 0, 0><<<dim3(4, 33), 256, 0, stream>>>(
      nullptr, H1, W2, W2 + 262144, mlp_b2, t, t, nullptr, M_ROWS, 256, MLP);

  head_kernel<<<Bsz, 1024, 0, stream>>>(t, head_w, head_b, out);
}

// Round 6
// 119.845 us; speedup vs baseline: 2.2365x; 1.0514x over previous
//
#include <hip/hip_runtime.h>
#include <math.h>

// ---------------- constants ----------------
#define Bsz   8
#define CHUNK 16
#define D     256      // d_model = num_heads = num_patches = 256
#define S     257      // seq len
#define MLP   1024
#define NCLS  1000
#define M_ROWS (Bsz * S)   // 2056

typedef unsigned int u32;
typedef unsigned short u16;
typedef __attribute__((ext_vector_type(8))) short bshort8;
typedef __attribute__((ext_vector_type(4))) float f32x4;

__device__ __forceinline__ float wave_sum(float v) {
  #pragma unroll
  for (int m = 1; m < 64; m <<= 1) v += __shfl_xor(v, m, 64);
  return v;
}

__device__ __forceinline__ u16 f2bf(float f) {
  u32 u = __float_as_uint(f);
  u += 0x7FFFu + ((u >> 16) & 1u);   // RNE
  return (u16)(u >> 16);
}
__device__ __forceinline__ float bf2f(u16 h) { return __uint_as_float(((u32)h) << 16); }
__device__ __forceinline__ u32 pk2(u16 a, u16 b) { return (u32)a | ((u32)b << 16); }

// raw v_exp_f32 — args bounded, no OCML guards needed
__device__ __forceinline__ float fexp2(float x) { return __builtin_amdgcn_exp2f(x); }

// ---------------- patch embed body (MFMA mini-GEMM, cls fused) ----------------
__device__ __forceinline__ void patch_body(int blk, int tid,
                                           const float* __restrict__ x,
                                           const float* __restrict__ pw,
                                           const float* __restrict__ pb,
                                           const float* __restrict__ pos,
                                           const float* __restrict__ ct,
                                           float* __restrict__ t,
                                           char* smem) {
  u16* sAh = (u16*)smem;
  u16* sAl = (u16*)(smem + 8192);
  u16* sBh = (u16*)(smem + 16384);
  u16* sBl = (u16*)(smem + 24576);
  const int n = blk >> 2;
  const int col0 = (blk & 3) * 64;
  const int pi = n >> 4, pj = n & 15;
  const int lane = tid & 63;
  const int w = tid >> 6;
  const int fr = lane & 15, g = lane >> 4;
  const int sr = tid >> 2, sc = tid & 3;
  const int arow = sr > 7 ? 7 : sr;   // M=8, clamp
  const u32 off0 = (u32)(sr * 128) + ((u32)((2 * sc)     ^ (sr & 7)) << 4);
  const u32 off1 = (u32)(sr * 128) + ((u32)((2 * sc + 1) ^ (sr & 7)) << 4);
  const float* ap32 = x + (size_t)arow * 65536 + (size_t)(pi * 16) * 256 + pj * 16;
  const float* bp32 = pw + (size_t)(col0 + sr) * 65536 + (size_t)n * 256 + sc * 16;

  if ((blk & 3) == 0 && tid < 8)
    t[((size_t)tid * S) * D + n] = ct[n] + pos[n];

  f32x4 acc = {0, 0, 0, 0}, ac2 = {0, 0, 0, 0};

  for (int k0 = 0; k0 < 256; k0 += 64) {
    const float* asrc = ap32 + (size_t)((k0 >> 4) + sc) * 256;
    float fa[16], fb[16];
    #pragma unroll
    for (int i = 0; i < 4; ++i) {
      float4 f4 = *(const float4*)(asrc + i * 4);
      fa[i*4+0] = f4.x; fa[i*4+1] = f4.y; fa[i*4+2] = f4.z; fa[i*4+3] = f4.w;
      float4 g4 = *(const float4*)(bp32 + k0 + i * 4);
      fb[i*4+0] = g4.x; fb[i*4+1] = g4.y; fb[i*4+2] = g4.z; fb[i*4+3] = g4.w;
    }
    u16 ah16[16], al16[16], bh16[16], bl16[16];
    #pragma unroll
    for (int i = 0; i < 16; ++i) {
      u16 h = f2bf(fa[i]); ah16[i] = h; al16[i] = f2bf(fa[i] - bf2f(h));
      u16 hb = f2bf(fb[i]); bh16[i] = hb; bl16[i] = f2bf(fb[i] - bf2f(hb));
    }
    __syncthreads();
    *(uint4*)((char*)sAh + off0) = make_uint4(pk2(ah16[0],ah16[1]), pk2(ah16[2],ah16[3]), pk2(ah16[4],ah16[5]), pk2(ah16[6],ah16[7]));
    *(uint4*)((char*)sAh + off1) = make_uint4(pk2(ah16[8],ah16[9]), pk2(ah16[10],ah16[11]), pk2(ah16[12],ah16[13]), pk2(ah16[14],ah16[15]));
    *(uint4*)((char*)sAl + off0) = make_uint4(pk2(al16[0],al16[1]), pk2(al16[2],al16[3]), pk2(al16[4],al16[5]), pk2(al16[6],al16[7]));
    *(uint4*)((char*)sAl + off1) = make_uint4(pk2(al16[8],al16[9]), pk2(al16[10],al16[11]), pk2(al16[12],al16[13]), pk2(al16[14],al16[15]));
    *(uint4*)((char*)sBh + off0) = make_uint4(pk2(bh16[0],bh16[1]), pk2(bh16[2],bh16[3]), pk2(bh16[4],bh16[5]), pk2(bh16[6],bh16[7]));
    *(uint4*)((char*)sBh + off1) = make_uint4(pk2(bh16[8],bh16[9]), pk2(bh16[10],bh16[11]), pk2(bh16[12],bh16[13]), pk2(bh16[14],bh16[15]));
    *(uint4*)((char*)sBl + off0) = make_uint4(pk2(bl16[0],bl16[1]), pk2(bl16[2],bl16[3]), pk2(bl16[4],bl16[5]), pk2(bl16[6],bl16[7]));
    *(uint4*)((char*)sBl + off1) = make_uint4(pk2(bl16[8],bl16[9]), pk2(bl16[10],bl16[11]), pk2(bl16[12],bl16[13]), pk2(bl16[14],bl16[15]));
    __syncthreads();
    #pragma unroll
    for (int ks = 0; ks < 2; ++ks) {
      int rA = fr;
      u32 oa = (u32)(rA * 128) + ((u32)((ks * 4 + g) ^ (rA & 7)) << 4);
      bshort8 ah = *(const bshort8*)((const char*)sAh + oa);
      bshort8 al = *(const bshort8*)((const char*)sAl + oa);
      int rB = w * 16 + fr;
      u32 ob = (u32)(rB * 128) + ((u32)((ks * 4 + g) ^ (rB & 7)) << 4);
      bshort8 bh = *(const bshort8*)((const char*)sBh + ob);
      bshort8 bl = *(const bshort8*)((const char*)sBl + ob);
      acc = __builtin_amdgcn_mfma_f32_16x16x32_bf16(ah, bh, acc, 0, 0, 0);
      ac2 = __builtin_amdgcn_mfma_f32_16x16x32_bf16(ah, bl, ac2, 0, 0, 0);
      ac2 = __builtin_amdgcn_mfma_f32_16x16x32_bf16(al, bh, ac2, 0, 0, 0);
    }
  }
  if (g < 2) {
    int h = col0 + w * 16 + fr;
    float addend = pb[h * 256 + n] + pos[(1 + h) * 256 + n];
    #pragma unroll
    for (int r = 0; r < 4; ++r) {
      int b = g * 4 + r;
      t[((size_t)b * S + 1 + h) * D + n] = acc[r] + ac2[r] + addend;
    }
  }
}

// ---------------- weight conversion bodies ----------------
__device__ __forceinline__ void conv_copy3_body(int blk, int tid,
                                                const float* __restrict__ wq,
                                                const float* __restrict__ wk,
                                                const float* __restrict__ wv,
                                                u16* __restrict__ W) {
  int wsel = blk >> 6, tile = blk & 63;
  const float* src = wsel == 0 ? wq : wsel == 1 ? wk : wv;
  u16* oh = W + wsel * 131072;
  u16* ol = oh + 65536;
  int r0 = (tile >> 3) * 32, c0 = (tile & 7) * 32;
  int tr = tid >> 3, tc = (tid & 7) * 4;
  const float4 f = *(const float4*)(src + (size_t)(r0 + tr) * 256 + c0 + tc);
  u16 h0 = f2bf(f.x), h1 = f2bf(f.y), h2 = f2bf(f.z), h3 = f2bf(f.w);
  u16 l0 = f2bf(f.x - bf2f(h0)), l1 = f2bf(f.y - bf2f(h1));
  u16 l2 = f2bf(f.z - bf2f(h2)), l3 = f2bf(f.w - bf2f(h3));
  size_t o = (size_t)(r0 + tr) * 256 + c0 + tc;
  *(uint2*)(oh + o) = make_uint2(pk2(h0, h1), pk2(h2, h3));
  *(uint2*)(ol + o) = make_uint2(pk2(l0, l1), pk2(l2, l3));
}

__device__ __forceinline__ void conv_trans_body(int blk, int tid,
                                                const float* __restrict__ src,
                                                u16* __restrict__ oh,
                                                u16* __restrict__ ol,
                                                int R, int Cc, char* smem) {
  float (*lt)[33] = (float(*)[33])smem;
  int tpc = Cc >> 5;
  int r0 = (blk / tpc) * 32, c0 = (blk % tpc) * 32;
  int tr = tid >> 3, tc = (tid & 7) * 4;
  float4 f = *(const float4*)(src + (size_t)(r0 + tr) * Cc + c0 + tc);
  lt[tr][tc + 0] = f.x; lt[tr][tc + 1] = f.y; lt[tr][tc + 2] = f.z; lt[tr][tc + 3] = f.w;
  __syncthreads();
  float a = lt[tc + 0][tr], b = lt[tc + 1][tr], c = lt[tc + 2][tr], d = lt[tc + 3][tr];
  u16 h0 = f2bf(a), h1 = f2bf(b), h2 = f2bf(c), h3 = f2bf(d);
  u16 l0 = f2bf(a - bf2f(h0)), l1 = f2bf(b - bf2f(h1));
  u16 l2 = f2bf(c - bf2f(h2)), l3 = f2bf(d - bf2f(h3));
  size_t o = (size_t)(c0 + tr) * R + r0 + tc;
  *(uint2*)(oh + o) = make_uint2(pk2(h0, h1), pk2(h2, h3));
  *(uint2*)(ol + o) = make_uint2(pk2(l0, l1), pk2(l2, l3));
}

// ---------------- stage0: patch (blocks 0..1023) + all weight conversions ----------------
__global__ __launch_bounds__(256) void stage0(const float* __restrict__ x,
                                              const float* __restrict__ pw,
                                              const float* __restrict__ pb,
                                              const float* __restrict__ pos,
                                              const float* __restrict__ ct,
                                              const float* __restrict__ wq,
                                              const float* __restrict__ wk,
                                              const float* __restrict__ wv,
                                              const float* __restrict__ proj_w,
                                              const float* __restrict__ mlp_w1,
                                              const float* __restrict__ mlp_w2,
                                              u16* __restrict__ Wqkv,
                                              u16* __restrict__ Wpj,
                                              u16* __restrict__ W1,
                                              u16* __restrict__ W2,
                                              float* __restrict__ t) {
  __shared__ __align__(16) char smem[32768];
  int blk = blockIdx.x, tid = threadIdx.x;
  if (blk < 1024)       patch_body(blk, tid, x, pw, pb, pos, ct, t, smem);
  else if (blk < 1216)  conv_copy3_body(blk - 1024, tid, wq, wk, wv, Wqkv);
  else if (blk < 1280)  conv_trans_body(blk - 1216, tid, proj_w, Wpj, Wpj + 65536, 256, 256, smem);
  else if (blk < 1536)  conv_trans_body(blk - 1280, tid, mlp_w1, W1, W1 + 262144, 256, 1024, smem);
  else                  conv_trans_body(blk - 1536, tid, mlp_w2, W2, W2 + 262144, 1024, 256, smem);
}

// fallback standalone kernels (small-ws path)
__global__ __launch_bounds__(256) void patch_gemm(const float* __restrict__ x,
                                                  const float* __restrict__ pw,
                                                  const float* __restrict__ pb,
                                                  const float* __restrict__ pos,
                                                  const float* __restrict__ ct,
                                                  float* __restrict__ t) {
  __shared__ __align__(16) char smem[32768];
  patch_body(blockIdx.x, threadIdx.x, x, pw, pb, pos, ct, t, smem);
}
__global__ __launch_bounds__(256) void conv_copy3(const float* __restrict__ wq,
                                                  const float* __restrict__ wk,
                                                  const float* __restrict__ wv,
                                                  u16* __restrict__ W) {
  conv_copy3_body(blockIdx.x, threadIdx.x, wq, wk, wv, W);
}
__global__ __launch_bounds__(256) void conv_trans(const float* __restrict__ src,
                                                  u16* __restrict__ oh,
                                                  u16* __restrict__ ol,
                                                  int R, int Cc) {
  __shared__ __align__(16) char smem[4352];
  conv_trans_body(blockIdx.x, threadIdx.x, src, oh, ol, R, Cc, smem);
}

// ---------------- layernorm -> split bf16 planes ----------------
__global__ __launch_bounds__(256) void ln_split(const float* __restrict__ in,
                                                u16* __restrict__ oh,
                                                u16* __restrict__ ol,
                                                const float* __restrict__ g,
                                                const float* __restrict__ b,
                                                int nrows) {
  int wid = threadIdx.x >> 6, lane = threadIdx.x & 63;
  int row = blockIdx.x * 4 + wid;
  if (row >= nrows) return;
  const float* p = in + (size_t)row * D;
  float4 v = *(const float4*)&p[lane * 4];
  float s = wave_sum(v.x + v.y + v.z + v.w);
  float mu = s * (1.0f / 256.0f);
  float dx = v.x - mu, dy = v.y - mu, dz = v.z - mu, dw = v.w - mu;
  float q = wave_sum(dx * dx + dy * dy + dz * dz + dw * dw);
  float rs = 1.0f / sqrtf(q * (1.0f / 256.0f) + 1e-5f);
  float4 gv = *(const float4*)&g[lane * 4];
  float4 bv = *(const float4*)&b[lane * 4];
  float o0 = dx * rs * gv.x + bv.x;
  float o1 = dy * rs * gv.y + bv.y;
  float o2 = dz * rs * gv.z + bv.z;
  float o3 = dw * rs * gv.w + bv.w;
  u16 h0 = f2bf(o0), h1 = f2bf(o1), h2 = f2bf(o2), h3 = f2bf(o3);
  u16 l0 = f2bf(o0 - bf2f(h0)), l1 = f2bf(o1 - bf2f(h1));
  u16 l2 = f2bf(o2 - bf2f(h2)), l3 = f2bf(o3 - bf2f(h3));
  size_t o = (size_t)row * D + lane * 4;
  *(uint2*)(oh + o) = make_uint2(pk2(h0, h1), pk2(h2, h3));
  *(uint2*)(ol + o) = make_uint2(pk2(l0, l1), pk2(l2, l3));
}

// ---------------- MFMA split-bf16 GEMM ----------------
// AMODE 0: A fp32, split inline (3 mfma). AMODE 1: A bf16 single (2 mfma).
// AMODE 2: A pre-split h/l planes (3 mfma, pure loads).
template<int AMODE, int HASBIAS, int RES, int GELU, int OUTBF, int OUTT>
__device__ __forceinline__ void gemm_core(const float* __restrict__ A32,
                                          const u16* __restrict__ A16,
                                          const u16* __restrict__ A16l,
                                          const u16* __restrict__ Bh,
                                          const u16* __restrict__ Bl,
                                          const float* __restrict__ bias,
                                          const float* __restrict__ res,
                                          float* __restrict__ Cf,
                                          u16* __restrict__ C16,
                                          int M, int N, int K, int row0, int col0) {
  __shared__ __align__(16) u16 sAh[4096];
  __shared__ __align__(16) u16 sAl[AMODE == 1 ? 8 : 4096];
  __shared__ __align__(16) u16 sBh[4096];
  __shared__ __align__(16) u16 sBl[4096];
  const int tid = threadIdx.x;
  const int lane = tid & 63;
  const int w = tid >> 6, wm = w >> 1, wn = w & 1;
  const int fr = lane & 15, g = lane >> 4;
  const int sr = tid >> 2, sc = tid & 3;
  int arow = row0 + sr; if (arow > M - 1) arow = M - 1;
  const u32 off0 = (u32)(sr * 128) + ((u32)((2 * sc)     ^ (sr & 7)) << 4);
  const u32 off1 = (u32)(sr * 128) + ((u32)((2 * sc + 1) ^ (sr & 7)) << 4);
  const float* ap32 = nullptr; const u16* ap16 = nullptr; const u16* ap16l = nullptr;
  if (AMODE == 0) ap32 = A32 + (size_t)arow * K + sc * 16;
  else {
    ap16 = A16 + (size_t)arow * K + sc * 16;
    if (AMODE == 2) ap16l = A16l + (size_t)arow * K + sc * 16;
  }
  const u16* bhp = Bh + (size_t)(col0 + sr) * K + sc * 16;
  const u16* blp = Bl + (size_t)(col0 + sr) * K + sc * 16;

  f32x4 acc[2][2], ac2[2][2];
  #pragma unroll
  for (int i = 0; i < 2; ++i)
    #pragma unroll
    for (int j = 0; j < 2; ++j) { acc[i][j] = (f32x4){0,0,0,0}; ac2[i][j] = (f32x4){0,0,0,0}; }

  for (int k0 = 0; k0 < K; k0 += 64) {
    uint4 wAh0, wAh1, wAl0, wAl1;
    if (AMODE == 0) {
      float fv[16];
      #pragma unroll
      for (int i = 0; i < 4; ++i) {
        float4 f4 = *(const float4*)(ap32 + k0 + i * 4);
        fv[i*4+0] = f4.x; fv[i*4+1] = f4.y; fv[i*4+2] = f4.z; fv[i*4+3] = f4.w;
      }
      u16 hh[16], ll[16];
      #pragma unroll
      for (int i = 0; i < 16; ++i) { u16 h = f2bf(fv[i]); hh[i] = h; ll[i] = f2bf(fv[i] - bf2f(h)); }
      wAh0 = make_uint4(pk2(hh[0],hh[1]), pk2(hh[2],hh[3]), pk2(hh[4],hh[5]), pk2(hh[6],hh[7]));
      wAh1 = make_uint4(pk2(hh[8],hh[9]), pk2(hh[10],hh[11]), pk2(hh[12],hh[13]), pk2(hh[14],hh[15]));
      wAl0 = make_uint4(pk2(ll[0],ll[1]), pk2(ll[2],ll[3]), pk2(ll[4],ll[5]), pk2(ll[6],ll[7]));
      wAl1 = make_uint4(pk2(ll[8],ll[9]), pk2(ll[10],ll[11]), pk2(ll[12],ll[13]), pk2(ll[14],ll[15]));
    } else if (AMODE == 2) {
      wAh0 = *(const uint4*)(ap16 + k0);
      wAh1 = *(const uint4*)(ap16 + k0 + 8);
      wAl0 = *(const uint4*)(ap16l + k0);
      wAl1 = *(const uint4*)(ap16l + k0 + 8);
    } else {
      wAh0 = *(const uint4*)(ap16 + k0);
      wAh1 = *(const uint4*)(ap16 + k0 + 8);
      wAl0 = wAh0; wAl1 = wAh1; // unused
    }
    uint4 wBh0 = *(const uint4*)(bhp + k0);
    uint4 wBh1 = *(const uint4*)(bhp + k0 + 8);
    uint4 wBl0 = *(const uint4*)(blp + k0);
    uint4 wBl1 = *(const uint4*)(blp + k0 + 8);
    __syncthreads();
    *(uint4*)((char*)sAh + off0) = wAh0;
    *(uint4*)((char*)sAh + off1) = wAh1;
    if (AMODE != 1) {
      *(uint4*)((char*)sAl + off0) = wAl0;
      *(uint4*)((char*)sAl + off1) = wAl1;
    }
    *(uint4*)((char*)sBh + off0) = wBh0;
    *(uint4*)((char*)sBh + off1) = wBh1;
    *(uint4*)((char*)sBl + off0) = wBl0;
    *(uint4*)((char*)sBl + off1) = wBl1;
    __syncthreads();
    #pragma unroll
    for (int ks = 0; ks < 2; ++ks) {
      bshort8 ah[2], al[2], bh2[2], bl2[2];
      #pragma unroll
      for (int f = 0; f < 2; ++f) {
        int rA = wm * 32 + f * 16 + fr;
        u32 oa = (u32)(rA * 128) + ((u32)((ks * 4 + g) ^ (rA & 7)) << 4);
        ah[f] = *(const bshort8*)((const char*)sAh + oa);
        if (AMODE != 1) al[f] = *(const bshort8*)((const char*)sAl + oa);
        int rB = wn * 32 + f * 16 + fr;
        u32 ob = (u32)(rB * 128) + ((u32)((ks * 4 + g) ^ (rB & 7)) << 4);
        bh2[f] = *(const bshort8*)((const char*)sBh + ob);
        bl2[f] = *(const bshort8*)((const char*)sBl + ob);
      }
      #pragma unroll
      for (int fi = 0; fi < 2; ++fi)
        #pragma unroll
        for (int fj = 0; fj < 2; ++fj) {
          acc[fi][fj] = __builtin_amdgcn_mfma_f32_16x16x32_bf16(ah[fi], bh2[fj], acc[fi][fj], 0, 0, 0);
          ac2[fi][fj] = __builtin_amdgcn_mfma_f32_16x16x32_bf16(ah[fi], bl2[fj], ac2[fi][fj], 0, 0, 0);
          if (AMODE != 1)
            ac2[fi][fj] = __builtin_amdgcn_mfma_f32_16x16x32_bf16(al[fi], bh2[fj], ac2[fi][fj], 0, 0, 0);
        }
    }
  }
  #pragma unroll
  for (int fi = 0; fi < 2; ++fi) {
    #pragma unroll
    for (int fj = 0; fj < 2; ++fj) {
      int col = col0 + wn * 32 + fj * 16 + fr;
      int rbase = row0 + wm * 32 + fi * 16 + g * 4;
      #pragma unroll
      for (int r = 0; r < 4; ++r) {
        int row = rbase + r;
        if (row < M) {
          float v = acc[fi][fj][r] + ac2[fi][fj][r];
          if (HASBIAS) v += bias[col];
          if (GELU) v = 0.5f * v * (1.0f + erff(v * 0.70710678118654752440f));
          if (RES)  v += res[(size_t)row * N + col];
          if (OUTT) {
            u32 bq = (u32)row / 257u;
            u32 sq = (u32)row - bq * 257u;
            Cf[((size_t)bq * 256 + col) * 257 + sq] = v;
          } else if (OUTBF) {
            C16[(size_t)row * N + col] = f2bf(v);
          } else {
            Cf[(size_t)row * N + col] = v;
          }
        }
      }
    }
  }
}

template<int AMODE, int HASBIAS, int RES, int GELU, int OUTBF>
__global__ __launch_bounds__(256) void gemm_k(const float* __restrict__ A32,
                                              const u16* __restrict__ A16,
                                              const u16* __restrict__ A16l,
                                              const u16* __restrict__ Bh,
                                              const u16* __restrict__ Bl,
                                              const float* __restrict__ bias,
                                              const float* __restrict__ res,
                                              float* __restrict__ Cf,
                                              u16* __restrict__ C16,
                                              int M, int N, int K) {
  gemm_core<AMODE, HASBIAS, RES, GELU, OUTBF, 0>(A32, A16, A16l, Bh, Bl, bias, res, Cf, C16,
                                                 M, N, K, blockIdx.y * 64, blockIdx.x * 64);
}

// QKV (A = pre-split LN output) with transposed output [b][h][s]
__global__ __launch_bounds__(256) void qkv_kernel(const u16* __restrict__ xnh,
                                                  const u16* __restrict__ xnl,
                                                  const u16* __restrict__ W,
                                                  float* __restrict__ q,
                                                  float* __restrict__ k,
                                                  float* __restrict__ v) {
  int z = blockIdx.z;
  const u16* Bh = W + z * 131072;
  const u16* Bl = Bh + 65536;
  float* C = z == 0 ? q : z == 1 ? k : v;
  gemm_core<2, 0, 0, 0, 0, 1>(nullptr, xnh, xnl, Bh, Bl, nullptr, nullptr, C, nullptr,
                              M_ROWS, 256, 256, blockIdx.y * 64, blockIdx.x * 64);
}

// ---------------- attention (d_head = 1), Q/K/V transposed [b][h][s] ----------------
__global__ __launch_bounds__(256) void attn_kernel(const float* __restrict__ Q,
                                                   const float* __restrict__ Kb,
                                                   const float* __restrict__ Vb,
                                                   float* __restrict__ O) {
  __shared__ __align__(16) float ks[S + 3], vs[S + 3];
  __shared__ float red[16];
  int h = blockIdx.x, b = blockIdx.y;
  size_t rowbase = ((size_t)b * 256 + h) * 257;
  int tid = threadIdx.x;
  int wid = tid >> 6, lane = tid & 63;
  for (int s = tid; s < S; s += 256) {
    ks[s] = Kb[rowbase + s];
    vs[s] = Vb[rowbase + s];
  }
  __syncthreads();
  float lmax = -1e30f, lmin = 1e30f;
  for (int s = tid; s < S; s += 256) {
    float kv = ks[s];
    lmax = fmaxf(lmax, kv); lmin = fminf(lmin, kv);
  }
  #pragma unroll
  for (int m = 1; m < 64; m <<= 1) {
    lmax = fmaxf(lmax, __shfl_xor(lmax, m, 64));
    lmin = fminf(lmin, __shfl_xor(lmin, m, 64));
  }
  if (lane == 0) { red[wid] = lmax; red[4 + wid] = lmin; }
  __syncthreads();
  float kmax = fmaxf(fmaxf(red[0], red[1]), fmaxf(red[2], red[3]));
  float kmin = fminf(fminf(red[4], red[5]), fminf(red[6], red[7]));

  const float L2E = 1.4426950408889634f;
  float qv = Q[rowbase + tid];
  float mm = qv >= 0.0f ? qv * kmax : qv * kmin;
  float ql = qv * L2E, nml = -mm * L2E;
  float den0 = 0, den1 = 0, den2 = 0, den3 = 0;
  float num0 = 0, num1 = 0, num2 = 0, num3 = 0;
  #pragma unroll 2
  for (int u = 0; u < 256; u += 8) {
    float4 k0 = *(const float4*)&ks[u];
    float4 k1 = *(const float4*)&ks[u + 4];
    float4 v0 = *(const float4*)&vs[u];
    float4 v1 = *(const float4*)&vs[u + 4];
    float e0 = fexp2(fmaf(ql, k0.x, nml));
    float e1 = fexp2(fmaf(ql, k0.y, nml));
    float e2 = fexp2(fmaf(ql, k0.z, nml));
    float e3 = fexp2(fmaf(ql, k0.w, nml));
    float e4 = fexp2(fmaf(ql, k1.x, nml));
    float e5 = fexp2(fmaf(ql, k1.y, nml));
    float e6 = fexp2(fmaf(ql, k1.z, nml));
    float e7 = fexp2(fmaf(ql, k1.w, nml));
    den0 += e0; num0 = fmaf(e0, v0.x, num0);
    den1 += e1; num1 = fmaf(e1, v0.y, num1);
    den2 += e2; num2 = fmaf(e2, v0.z, num2);
    den3 += e3; num3 = fmaf(e3, v0.w, num3);
    den0 += e4; num0 = fmaf(e4, v1.x, num0);
    den1 += e5; num1 = fmaf(e5, v1.y, num1);
    den2 += e6; num2 = fmaf(e6, v1.z, num2);
    den3 += e7; num3 = fmaf(e7, v1.w, num3);
  }
  {
    float e = fexp2(fmaf(ql, ks[256], nml));
    den0 += e; num0 = fmaf(e, vs[256], num0);
  }
  float den = (den0 + den1) + (den2 + den3);
  float num = (num0 + num1) + (num2 + num3);
  O[((size_t)b * S + tid) * D + h] = num / den;

  // row 256, cooperative across the block
  float qv2 = Q[rowbase + 256];
  float mm2 = qv2 >= 0.0f ? qv2 * kmax : qv2 * kmin;
  float ql2 = qv2 * L2E, nml2 = -mm2 * L2E;
  float e = fexp2(fmaf(ql2, ks[tid], nml2));
  float dp = e, np = e * vs[tid];
  if (tid == 0) {
    float e2 = fexp2(fmaf(ql2, ks[256], nml2));
    dp += e2; np = fmaf(e2, vs[256], np);
  }
  dp = wave_sum(dp); np = wave_sum(np);
  if (lane == 0) { red[8 + wid] = dp; red[12 + wid] = np; }
  __syncthreads();
  if (tid == 0) {
    float dd = (red[8] + red[9]) + (red[10] + red[11]);
    float nn = (red[12] + red[13]) + (red[14] + red[15]);
    O[((size_t)b * S + 256) * D + h] = nn / dd;
  }
}

// ---------------- head: logits + softmax, 1024 threads ----------------
__global__ __launch_bounds__(1024) void head_kernel(const float* __restrict__ t,
                                                    const float* __restrict__ hw,
                                                    const float* __restrict__ hb,
                                                    float* __restrict__ out) {
  __shared__ float trow[D];
  __shared__ float red[16];
  int b = blockIdx.x, tid = threadIdx.x;
  if (tid < D) trow[tid] = t[((size_t)b * S) * D + tid];
  __syncthreads();
  float acc = 0.0f;
  int n = tid;
  if (n < NCLS) {
    float a0 = 0, a1 = 0, a2 = 0, a3 = 0;
    #pragma unroll 4
    for (int d = 0; d < D; d += 4) {
      a0 = fmaf(trow[d + 0], hw[(size_t)(d + 0) * NCLS + n], a0);
      a1 = fmaf(trow[d + 1], hw[(size_t)(d + 1) * NCLS + n], a1);
      a2 = fmaf(trow[d + 2], hw[(size_t)(d + 2) * NCLS + n], a2);
      a3 = fmaf(trow[d + 3], hw[(size_t)(d + 3) * NCLS + n], a3);
    }
    acc = hb[n] + ((a0 + a1) + (a2 + a3));
  }
  float m = (n < NCLS) ? acc : -1e30f;
  #pragma unroll
  for (int s = 1; s < 64; s <<= 1) m = fmaxf(m, __shfl_xor(m, s, 64));
  int wid = tid >> 6, lane = tid & 63;
  if (lane == 0) red[wid] = m;
  __syncthreads();
  if (tid == 0) {
    float mm = red[0];
    #pragma unroll
    for (int i = 1; i < 16; ++i) mm = fmaxf(mm, red[i]);
    red[0] = mm;
  }
  __syncthreads();
  float gmax = red[0];
  float e = (n < NCLS) ? expf(acc - gmax) : 0.0f;
  float ss = e;
  #pragma unroll
  for (int s = 1; s < 64; s <<= 1) ss += __shfl_xor(ss, s, 64);
  __syncthreads();
  if (lane == 0) red[wid] = ss;
  __syncthreads();
  if (tid == 0) {
    float t2 = 0.0f;
    #pragma unroll
    for (int i = 0; i < 16; ++i) t2 += red[i];
    red[0] = t2;
  }
  __syncthreads();
  if (n < NCLS) out[(size_t)b * NCLS + n] = e / red[0];
}

// ---------------- launch ----------------
extern "C" void kernel_launch(void* const* d_in, const int* in_sizes, int n_in,
                              void* d_out, int out_size, void* d_ws, size_t ws_size,
                              hipStream_t stream) {
  const float* x        = (const float*)d_in[0];
  const float* class_tk = (const float*)d_in[1];
  const float* pos_emb  = (const float*)d_in[2];
  const float* patch_w  = (const float*)d_in[3];
  const float* patch_b  = (const float*)d_in[4];
  const float* wq       = (const float*)d_in[5];
  const float* wk       = (const float*)d_in[6];
  const float* wv       = (const float*)d_in[7];
  const float* proj_w   = (const float*)d_in[8];
  const float* proj_b   = (const float*)d_in[9];
  const float* mlp_w1   = (const float*)d_in[10];
  const float* mlp_b1   = (const float*)d_in[11];
  const float* mlp_w2   = (const float*)d_in[12];
  const float* mlp_b2   = (const float*)d_in[13];
  const float* ln1_g    = (const float*)d_in[14];
  const float* ln1_b    = (const float*)d_in[15];
  const float* ln2_g    = (const float*)d_in[16];
  const float* ln2_b    = (const float*)d_in[17];
  const float* head_w   = (const float*)d_in[18];
  const float* head_b   = (const float*)d_in[19];
  float* out = (float*)d_out;

  float* ws = (float*)d_ws;
  const size_t NTOK = (size_t)M_ROWS * D;   // 526336
  float* t   = ws;
  u16*  xnh  = (u16*)(ws + NTOK);          // LN output, split planes
  u16*  xnl  = xnh + NTOK;
  float* q  = ws + 2 * NTOK;   // transposed [b][h][s]
  float* kk = ws + 3 * NTOK;   // transposed
  float* v  = ws + 4 * NTOK;   // transposed
  float* o  = ws + 5 * NTOK;   // row-major [b*S+s][h]
  u16* H1;                     // 2056*1024 u16 = 4.2 MB
  u16 *Wqkv, *Wpj, *W1, *W2;

  const size_t tail_need = 6 * NTOK * 4 + 8 * 65536 * 2 + 4 * 262144 * 2;
  bool tail = ws_size >= tail_need;
  if (tail) {
    u16* wbase = (u16*)(ws + 6 * NTOK);
    Wqkv = wbase;                  // 6*65536
    Wpj  = wbase + 6 * 65536;      // 2*65536
    W1   = wbase + 8 * 65536;      // 2*262144
    W2   = W1 + 2 * 262144;        // 2*262144
    H1   = (u16*)(ws + 2 * NTOK);  // q/k region, dead after attn
  } else {
    Wqkv = (u16*)(ws + 5 * NTOK);
    W1   = (u16*)(ws + 2 * NTOK);
    Wpj  = (u16*)(ws + 4 * NTOK);
    H1   = (u16*)(ws + 3 * NTOK);
    W2   = (u16*)(ws + 1 * NTOK) + 2 * NTOK;  // after xnh/xnl in xn region? no room: fallback uses t-region trick below
  }

  if (tail) {
    stage0<<<1792, 256, 0, stream>>>(x, patch_w, patch_b, pos_emb, class_tk,
                                     wq, wk, wv, proj_w, mlp_w1, mlp_w2,
                                     Wqkv, Wpj, W1, W2, t);
  } else {
    conv_copy3<<<192, 256, 0, stream>>>(wq, wk, wv, Wqkv);
    patch_gemm<<<1024, 256, 0, stream>>>(x, patch_w, patch_b, pos_emb, class_tk, t);
  }

  ln_split<<<(M_ROWS + 3) / 4, 256, 0, stream>>>(t, xnh, xnl, ln1_g, ln1_b, M_ROWS);

  qkv_kernel<<<dim3(4, 33, 3), 256, 0, stream>>>(xnh, xnl, Wqkv, q, kk, v);

  attn_kernel<<<dim3(256, Bsz), 256, 0, stream>>>(q, kk, v, o);

  if (!tail) {
    W2 = (u16*)(ws + 3 * NTOK);   // kk region, dead after attn (H1 moves to 2N)
    H1 = (u16*)(ws + 2 * NTOK);
    conv_trans<<<64, 256, 0, stream>>>(proj_w, Wpj, Wpj + 65536, 256, 256);
    conv_trans<<<256, 256, 0, stream>>>(mlp_w1, W1, W1 + 262144, 256, 1024);
  }

  gemm_k<0, 1, 1, 0, 0><<<dim3(4, 33), 256, 0, stream>>>(
      o, nullptr, nullptr, Wpj, Wpj + 65536, proj_b, t, t, nullptr, M_ROWS, 256, 256);

  ln_split<<<(M_ROWS + 3) / 4, 256, 0, stream>>>(t, xnh, xnl, ln2_g, ln2_b, M_ROWS);

  if (!tail) {
    conv_trans<<<256, 256, 0, stream>>>(mlp_w2, W2, W2 + 262144, 1024, 256);
  }

  gemm_k<2, 1, 0, 1, 1><<<dim3(16, 33), 256, 0, stream>>>(
      nullptr, xnh, xnl, W1, W1 + 262144, mlp_b1, nullptr, nullptr, H1, M_ROWS, MLP, 256);

  gemm_k<1, 1, 1, 0, 0><<<dim3(4, 33), 256, 0, stream>>>(
      nullptr, H1, nullptr, W2, W2 + 262144, mlp_b2, t, t, nullptr, M_ROWS, 256, MLP);

  head_kernel<<<Bsz, 1024, 0, stream>>>(t, head_w, head_b, out);
}

// Round 7
// 104.658 us; speedup vs baseline: 2.5610x; 1.1451x over previous
//
#include <hip/hip_runtime.h>
#include <math.h>

// ---------------- constants ----------------
#define Bsz   8
#define D     256      // d_model = num_heads = num_patches = 256
#define S     257      // seq len
#define MLP   1024
#define NCLS  1000
#define M_ROWS (Bsz * S)   // 2056

typedef unsigned int u32;
typedef unsigned short u16;
typedef __attribute__((ext_vector_type(8))) short bshort8;
typedef __attribute__((ext_vector_type(4))) float f32x4;

__device__ __forceinline__ float wave_sum(float v) {
  #pragma unroll
  for (int m = 1; m < 64; m <<= 1) v += __shfl_xor(v, m, 64);
  return v;
}

__device__ __forceinline__ u16 f2bf(float f) {
  u32 u = __float_as_uint(f);
  u += 0x7FFFu + ((u >> 16) & 1u);   // RNE
  return (u16)(u >> 16);
}
__device__ __forceinline__ float bf2f(u16 h) { return __uint_as_float(((u32)h) << 16); }
__device__ __forceinline__ u32 pk2(u16 a, u16 b) { return (u32)a | ((u32)b << 16); }
__device__ __forceinline__ float fexp2(float x) { return __builtin_amdgcn_exp2f(x); }

// ---------------- patch embed body (MFMA mini-GEMM, cls fused) ----------------
__device__ __forceinline__ void patch_body(int blk, int tid,
                                           const float* __restrict__ x,
                                           const float* __restrict__ pw,
                                           const float* __restrict__ pb,
                                           const float* __restrict__ pos,
                                           const float* __restrict__ ct,
                                           float* __restrict__ t,
                                           char* smem) {
  u16* sAh = (u16*)smem;
  u16* sAl = (u16*)(smem + 8192);
  u16* sBh = (u16*)(smem + 16384);
  u16* sBl = (u16*)(smem + 24576);
  const int n = blk >> 2;
  const int col0 = (blk & 3) * 64;
  const int pi = n >> 4, pj = n & 15;
  const int lane = tid & 63;
  const int w = tid >> 6;
  const int fr = lane & 15, g = lane >> 4;
  const int sr = tid >> 2, sc = tid & 3;
  const int arow = sr > 7 ? 7 : sr;   // M=8, clamp
  const u32 off0 = (u32)(sr * 128) + ((u32)((2 * sc)     ^ (sr & 7)) << 4);
  const u32 off1 = (u32)(sr * 128) + ((u32)((2 * sc + 1) ^ (sr & 7)) << 4);
  const float* ap32 = x + (size_t)arow * 65536 + (size_t)(pi * 16) * 256 + pj * 16;
  const float* bp32 = pw + (size_t)(col0 + sr) * 65536 + (size_t)n * 256 + sc * 16;

  if ((blk & 3) == 0 && tid < 8)
    t[((size_t)tid * S) * D + n] = ct[n] + pos[n];

  f32x4 acc = {0, 0, 0, 0}, ac2 = {0, 0, 0, 0};

  for (int k0 = 0; k0 < 256; k0 += 64) {
    const float* asrc = ap32 + (size_t)((k0 >> 4) + sc) * 256;
    float fa[16], fb[16];
    #pragma unroll
    for (int i = 0; i < 4; ++i) {
      float4 f4 = *(const float4*)(asrc + i * 4);
      fa[i*4+0] = f4.x; fa[i*4+1] = f4.y; fa[i*4+2] = f4.z; fa[i*4+3] = f4.w;
      float4 g4 = *(const float4*)(bp32 + k0 + i * 4);
      fb[i*4+0] = g4.x; fb[i*4+1] = g4.y; fb[i*4+2] = g4.z; fb[i*4+3] = g4.w;
    }
    u16 ah16[16], al16[16], bh16[16], bl16[16];
    #pragma unroll
    for (int i = 0; i < 16; ++i) {
      u16 h = f2bf(fa[i]); ah16[i] = h; al16[i] = f2bf(fa[i] - bf2f(h));
      u16 hb = f2bf(fb[i]); bh16[i] = hb; bl16[i] = f2bf(fb[i] - bf2f(hb));
    }
    __syncthreads();
    *(uint4*)((char*)sAh + off0) = make_uint4(pk2(ah16[0],ah16[1]), pk2(ah16[2],ah16[3]), pk2(ah16[4],ah16[5]), pk2(ah16[6],ah16[7]));
    *(uint4*)((char*)sAh + off1) = make_uint4(pk2(ah16[8],ah16[9]), pk2(ah16[10],ah16[11]), pk2(ah16[12],ah16[13]), pk2(ah16[14],ah16[15]));
    *(uint4*)((char*)sAl + off0) = make_uint4(pk2(al16[0],al16[1]), pk2(al16[2],al16[3]), pk2(al16[4],al16[5]), pk2(al16[6],al16[7]));
    *(uint4*)((char*)sAl + off1) = make_uint4(pk2(al16[8],al16[9]), pk2(al16[10],al16[11]), pk2(al16[12],al16[13]), pk2(al16[14],al16[15]));
    *(uint4*)((char*)sBh + off0) = make_uint4(pk2(bh16[0],bh16[1]), pk2(bh16[2],bh16[3]), pk2(bh16[4],bh16[5]), pk2(bh16[6],bh16[7]));
    *(uint4*)((char*)sBh + off1) = make_uint4(pk2(bh16[8],bh16[9]), pk2(bh16[10],bh16[11]), pk2(bh16[12],bh16[13]), pk2(bh16[14],bh16[15]));
    *(uint4*)((char*)sBl + off0) = make_uint4(pk2(bl16[0],bl16[1]), pk2(bl16[2],bl16[3]), pk2(bl16[4],bl16[5]), pk2(bl16[6],bl16[7]));
    *(uint4*)((char*)sBl + off1) = make_uint4(pk2(bl16[8],bl16[9]), pk2(bl16[10],bl16[11]), pk2(bl16[12],bl16[13]), pk2(bl16[14],bl16[15]));
    __syncthreads();
    #pragma unroll
    for (int ks = 0; ks < 2; ++ks) {
      int rA = fr;
      u32 oa = (u32)(rA * 128) + ((u32)((ks * 4 + g) ^ (rA & 7)) << 4);
      bshort8 ah = *(const bshort8*)((const char*)sAh + oa);
      bshort8 al = *(const bshort8*)((const char*)sAl + oa);
      int rB = w * 16 + fr;
      u32 ob = (u32)(rB * 128) + ((u32)((ks * 4 + g) ^ (rB & 7)) << 4);
      bshort8 bh = *(const bshort8*)((const char*)sBh + ob);
      bshort8 bl = *(const bshort8*)((const char*)sBl + ob);
      acc = __builtin_amdgcn_mfma_f32_16x16x32_bf16(ah, bh, acc, 0, 0, 0);
      ac2 = __builtin_amdgcn_mfma_f32_16x16x32_bf16(ah, bl, ac2, 0, 0, 0);
      ac2 = __builtin_amdgcn_mfma_f32_16x16x32_bf16(al, bh, ac2, 0, 0, 0);
    }
  }
  if (g < 2) {
    int h = col0 + w * 16 + fr;
    float addend = pb[h * 256 + n] + pos[(1 + h) * 256 + n];
    #pragma unroll
    for (int r = 0; r < 4; ++r) {
      int b = g * 4 + r;
      t[((size_t)b * S + 1 + h) * D + n] = acc[r] + ac2[r] + addend;
    }
  }
}

// K/V weight split-convert: [h][d] row-major stays [N][K]
__device__ __forceinline__ void conv_copy2_body(int blk, int tid,
                                                const float* __restrict__ wk,
                                                const float* __restrict__ wv,
                                                u16* __restrict__ W) {
  int wsel = blk >> 6, tile = blk & 63;
  const float* src = wsel == 0 ? wk : wv;
  u16* oh = W + wsel * 131072;
  u16* ol = oh + 65536;
  int r0 = (tile >> 3) * 32, c0 = (tile & 7) * 32;
  int tr = tid >> 3, tc = (tid & 7) * 4;
  const float4 f = *(const float4*)(src + (size_t)(r0 + tr) * 256 + c0 + tc);
  u16 h0 = f2bf(f.x), h1 = f2bf(f.y), h2 = f2bf(f.z), h3 = f2bf(f.w);
  u16 l0 = f2bf(f.x - bf2f(h0)), l1 = f2bf(f.y - bf2f(h1));
  u16 l2 = f2bf(f.z - bf2f(h2)), l3 = f2bf(f.w - bf2f(h3));
  size_t o = (size_t)(r0 + tr) * 256 + c0 + tc;
  *(uint2*)(oh + o) = make_uint2(pk2(h0, h1), pk2(h2, h3));
  *(uint2*)(ol + o) = make_uint2(pk2(l0, l1), pk2(l2, l3));
}

// ---------------- stage0: patch (0..1023) + K/V weight conv (1024..1151) ----------------
__global__ __launch_bounds__(256) void stage0(const float* __restrict__ x,
                                              const float* __restrict__ pw,
                                              const float* __restrict__ pb,
                                              const float* __restrict__ pos,
                                              const float* __restrict__ ct,
                                              const float* __restrict__ wk,
                                              const float* __restrict__ wv,
                                              u16* __restrict__ Wkv,
                                              float* __restrict__ t) {
  __shared__ __align__(16) char smem[32768];
  int blk = blockIdx.x, tid = threadIdx.x;
  if (blk < 1024) patch_body(blk, tid, x, pw, pb, pos, ct, t, smem);
  else            conv_copy2_body(blk - 1024, tid, wk, wv, Wkv);
}

// ---------------- layernorm -> split bf16 planes ----------------
__global__ __launch_bounds__(256) void ln_split(const float* __restrict__ in,
                                                u16* __restrict__ oh,
                                                u16* __restrict__ ol,
                                                const float* __restrict__ g,
                                                const float* __restrict__ b,
                                                int nrows) {
  int wid = threadIdx.x >> 6, lane = threadIdx.x & 63;
  int row = blockIdx.x * 4 + wid;
  if (row >= nrows) return;
  const float* p = in + (size_t)row * D;
  float4 v = *(const float4*)&p[lane * 4];
  float s = wave_sum(v.x + v.y + v.z + v.w);
  float mu = s * (1.0f / 256.0f);
  float dx = v.x - mu, dy = v.y - mu, dz = v.z - mu, dw = v.w - mu;
  float q = wave_sum(dx * dx + dy * dy + dz * dz + dw * dw);
  float rs = 1.0f / sqrtf(q * (1.0f / 256.0f) + 1e-5f);
  float4 gv = *(const float4*)&g[lane * 4];
  float4 bv = *(const float4*)&b[lane * 4];
  float o0 = dx * rs * gv.x + bv.x;
  float o1 = dy * rs * gv.y + bv.y;
  float o2 = dz * rs * gv.z + bv.z;
  float o3 = dw * rs * gv.w + bv.w;
  u16 h0 = f2bf(o0), h1 = f2bf(o1), h2 = f2bf(o2), h3 = f2bf(o3);
  u16 l0 = f2bf(o0 - bf2f(h0)), l1 = f2bf(o1 - bf2f(h1));
  u16 l2 = f2bf(o2 - bf2f(h2)), l3 = f2bf(o3 - bf2f(h3));
  size_t o = (size_t)row * D + lane * 4;
  *(uint2*)(oh + o) = make_uint2(pk2(h0, h1), pk2(h2, h3));
  *(uint2*)(ol + o) = make_uint2(pk2(l0, l1), pk2(l2, l3));
}

// ---------------- MFMA split-bf16 GEMM core (AMODE2: pre-split A planes) ----------------
template<int AMODE, int OUTT>
__device__ __forceinline__ void gemm_core(const u16* __restrict__ A16,
                                          const u16* __restrict__ A16l,
                                          const u16* __restrict__ Bh,
                                          const u16* __restrict__ Bl,
                                          float* __restrict__ Cf,
                                          int M, int N, int K, int row0, int col0) {
  __shared__ __align__(16) u16 sAh[4096];
  __shared__ __align__(16) u16 sAl[4096];
  __shared__ __align__(16) u16 sBh[4096];
  __shared__ __align__(16) u16 sBl[4096];
  const int tid = threadIdx.x;
  const int lane = tid & 63;
  const int w = tid >> 6, wm = w >> 1, wn = w & 1;
  const int fr = lane & 15, g = lane >> 4;
  const int sr = tid >> 2, sc = tid & 3;
  int arow = row0 + sr; if (arow > M - 1) arow = M - 1;
  const u32 off0 = (u32)(sr * 128) + ((u32)((2 * sc)     ^ (sr & 7)) << 4);
  const u32 off1 = (u32)(sr * 128) + ((u32)((2 * sc + 1) ^ (sr & 7)) << 4);
  const u16* ap16  = A16  + (size_t)arow * K + sc * 16;
  const u16* ap16l = A16l + (size_t)arow * K + sc * 16;
  const u16* bhp = Bh + (size_t)(col0 + sr) * K + sc * 16;
  const u16* blp = Bl + (size_t)(col0 + sr) * K + sc * 16;

  f32x4 acc[2][2], ac2[2][2];
  #pragma unroll
  for (int i = 0; i < 2; ++i)
    #pragma unroll
    for (int j = 0; j < 2; ++j) { acc[i][j] = (f32x4){0,0,0,0}; ac2[i][j] = (f32x4){0,0,0,0}; }

  for (int k0 = 0; k0 < K; k0 += 64) {
    uint4 wAh0 = *(const uint4*)(ap16 + k0);
    uint4 wAh1 = *(const uint4*)(ap16 + k0 + 8);
    uint4 wAl0 = *(const uint4*)(ap16l + k0);
    uint4 wAl1 = *(const uint4*)(ap16l + k0 + 8);
    uint4 wBh0 = *(const uint4*)(bhp + k0);
    uint4 wBh1 = *(const uint4*)(bhp + k0 + 8);
    uint4 wBl0 = *(const uint4*)(blp + k0);
    uint4 wBl1 = *(const uint4*)(blp + k0 + 8);
    __syncthreads();
    *(uint4*)((char*)sAh + off0) = wAh0;
    *(uint4*)((char*)sAh + off1) = wAh1;
    *(uint4*)((char*)sAl + off0) = wAl0;
    *(uint4*)((char*)sAl + off1) = wAl1;
    *(uint4*)((char*)sBh + off0) = wBh0;
    *(uint4*)((char*)sBh + off1) = wBh1;
    *(uint4*)((char*)sBl + off0) = wBl0;
    *(uint4*)((char*)sBl + off1) = wBl1;
    __syncthreads();
    #pragma unroll
    for (int ks = 0; ks < 2; ++ks) {
      bshort8 ah[2], al[2], bh2[2], bl2[2];
      #pragma unroll
      for (int f = 0; f < 2; ++f) {
        int rA = wm * 32 + f * 16 + fr;
        u32 oa = (u32)(rA * 128) + ((u32)((ks * 4 + g) ^ (rA & 7)) << 4);
        ah[f] = *(const bshort8*)((const char*)sAh + oa);
        al[f] = *(const bshort8*)((const char*)sAl + oa);
        int rB = wn * 32 + f * 16 + fr;
        u32 ob = (u32)(rB * 128) + ((u32)((ks * 4 + g) ^ (rB & 7)) << 4);
        bh2[f] = *(const bshort8*)((const char*)sBh + ob);
        bl2[f] = *(const bshort8*)((const char*)sBl + ob);
      }
      #pragma unroll
      for (int fi = 0; fi < 2; ++fi)
        #pragma unroll
        for (int fj = 0; fj < 2; ++fj) {
          acc[fi][fj] = __builtin_amdgcn_mfma_f32_16x16x32_bf16(ah[fi], bh2[fj], acc[fi][fj], 0, 0, 0);
          ac2[fi][fj] = __builtin_amdgcn_mfma_f32_16x16x32_bf16(ah[fi], bl2[fj], ac2[fi][fj], 0, 0, 0);
          ac2[fi][fj] = __builtin_amdgcn_mfma_f32_16x16x32_bf16(al[fi], bh2[fj], ac2[fi][fj], 0, 0, 0);
        }
    }
  }
  #pragma unroll
  for (int fi = 0; fi < 2; ++fi) {
    #pragma unroll
    for (int fj = 0; fj < 2; ++fj) {
      int col = col0 + wn * 32 + fj * 16 + fr;
      int rbase = row0 + wm * 32 + fi * 16 + g * 4;
      #pragma unroll
      for (int r = 0; r < 4; ++r) {
        int row = rbase + r;
        if (row < M) {
          float v = acc[fi][fj][r] + ac2[fi][fj][r];
          if (OUTT) {
            u32 bq = (u32)row / 257u;
            u32 sq = (u32)row - bq * 257u;
            Cf[((size_t)bq * 256 + col) * 257 + sq] = v;
          } else {
            Cf[(size_t)row * N + col] = v;
          }
        }
      }
    }
  }
}

// K/V GEMM with transposed output [b][h][s]
__global__ __launch_bounds__(256) void kv_kernel(const u16* __restrict__ xnh,
                                                 const u16* __restrict__ xnl,
                                                 const u16* __restrict__ Wkv,
                                                 float* __restrict__ kk,
                                                 float* __restrict__ v) {
  int z = blockIdx.z;
  const u16* Bh = Wkv + z * 131072;
  const u16* Bl = Bh + 65536;
  float* C = z == 0 ? kk : v;
  gemm_core<2, 1>(xnh, xnl, Bh, Bl, C, M_ROWS, 256, 256, blockIdx.y * 64, blockIdx.x * 64);
}

// ---------------- attention, cls query only: o_cls[b][h] ----------------
__global__ __launch_bounds__(256) void attn_cls(const u16* __restrict__ xnh,
                                                const u16* __restrict__ xnl,
                                                const float* __restrict__ wq,
                                                const float* __restrict__ Kb,
                                                const float* __restrict__ Vb,
                                                float* __restrict__ o_cls) {
  __shared__ float red[20];
  int h = blockIdx.x, b = blockIdx.y;
  int tid = threadIdx.x, wid = tid >> 6, lane = tid & 63;
  size_t xbase = (size_t)b * 257 * 256;
  float xv = bf2f(xnh[xbase + tid]) + bf2f(xnl[xbase + tid]);
  float part = xv * wq[h * 256 + tid];
  part = wave_sum(part);
  size_t rowbase = ((size_t)b * 256 + h) * 257;
  float kt = Kb[rowbase + tid], vt = Vb[rowbase + tid];
  float k2 = 0.f, v2 = 0.f;
  if (tid == 0) { k2 = Kb[rowbase + 256]; v2 = Vb[rowbase + 256]; }
  float lmax = tid == 0 ? fmaxf(kt, k2) : kt;
  float lmin = tid == 0 ? fminf(kt, k2) : kt;
  #pragma unroll
  for (int m = 1; m < 64; m <<= 1) {
    lmax = fmaxf(lmax, __shfl_xor(lmax, m, 64));
    lmin = fminf(lmin, __shfl_xor(lmin, m, 64));
  }
  if (lane == 0) { red[wid] = part; red[4 + wid] = lmax; red[8 + wid] = lmin; }
  __syncthreads();
  float q = (red[0] + red[1]) + (red[2] + red[3]);
  float kmax = fmaxf(fmaxf(red[4], red[5]), fmaxf(red[6], red[7]));
  float kmin = fminf(fminf(red[8], red[9]), fminf(red[10], red[11]));
  const float L2E = 1.4426950408889634f;
  float m = q >= 0.f ? q * kmax : q * kmin;
  float ql = q * L2E, nml = -m * L2E;
  float e = fexp2(fmaf(ql, kt, nml));
  float den = e, num = e * vt;
  if (tid == 0) {
    float e2 = fexp2(fmaf(ql, k2, nml));
    den += e2; num = fmaf(e2, v2, num);
  }
  den = wave_sum(den); num = wave_sum(num);
  if (lane == 0) { red[12 + wid] = den; red[16 + wid] = num; }
  __syncthreads();
  if (tid == 0) {
    float dd = (red[12] + red[13]) + (red[14] + red[15]);
    float nn = (red[16] + red[17]) + (red[18] + red[19]);
    o_cls[b * 256 + h] = nn / dd;
  }
}

// ---------------- tail: proj+res -> ln2 -> mlp1+gelu -> mlp2+res -> head+softmax ----------------
__global__ __launch_bounds__(1024) void tail_kernel(const float* __restrict__ o_cls,
                                                    const float* __restrict__ proj_w,
                                                    const float* __restrict__ proj_b,
                                                    const float* __restrict__ t,
                                                    const float* __restrict__ ln2_g,
                                                    const float* __restrict__ ln2_b,
                                                    const float* __restrict__ mlp_w1,
                                                    const float* __restrict__ mlp_b1,
                                                    const float* __restrict__ mlp_w2,
                                                    const float* __restrict__ mlp_b2,
                                                    const float* __restrict__ head_w,
                                                    const float* __restrict__ head_b,
                                                    float* __restrict__ out) {
  __shared__ float orow[256], tn[256], xn2[256], hrow[1024];
  __shared__ float part4[4][256];
  __shared__ float red[16];
  int b = blockIdx.x, tid = threadIdx.x;
  int n = tid & 255, pp = tid >> 8;
  int wid = tid >> 6, lane = tid & 63;
  if (tid < 256) {
    orow[tid] = o_cls[b * 256 + tid];
    tn[tid]   = t[((size_t)b * S) * D + tid];
  }
  __syncthreads();
  // proj: tn += orow @ proj_w + proj_b   (proj_w [256h][256n], coalesced over n)
  {
    float s = 0.f;
    #pragma unroll 4
    for (int hh = pp * 64; hh < pp * 64 + 64; ++hh)
      s = fmaf(orow[hh], proj_w[(size_t)hh * 256 + n], s);
    part4[pp][n] = s;
  }
  __syncthreads();
  float tval = 0.f;
  if (tid < 256) {
    tval = tn[tid] + proj_b[tid] +
           ((part4[0][tid] + part4[1][tid]) + (part4[2][tid] + part4[3][tid]));
    tn[tid] = tval;
    float s = wave_sum(tval);
    if (lane == 0) red[wid] = s;
  }
  __syncthreads();
  float mu = ((red[0] + red[1]) + (red[2] + red[3])) * (1.0f / 256.0f);
  if (tid < 256) {
    float d2 = tval - mu;
    float s = wave_sum(d2 * d2);
    if (lane == 0) red[4 + wid] = s;
  }
  __syncthreads();
  {
    float var = ((red[4] + red[5]) + (red[6] + red[7])) * (1.0f / 256.0f);
    float rs = 1.0f / sqrtf(var + 1e-5f);
    if (tid < 256) xn2[tid] = (tval - mu) * rs * ln2_g[tid] + ln2_b[tid];
  }
  __syncthreads();
  // mlp1 + exact gelu: hrow[j], j = tid  (mlp_w1 [256d][1024j], coalesced over j)
  {
    float s = mlp_b1[tid];
    #pragma unroll 4
    for (int d2 = 0; d2 < 256; ++d2)
      s = fmaf(xn2[d2], mlp_w1[(size_t)d2 * 1024 + tid], s);
    hrow[tid] = 0.5f * s * (1.0f + erff(s * 0.70710678118654752440f));
  }
  __syncthreads();
  // mlp2: tn += hrow @ mlp_w2 + mlp_b2   (mlp_w2 [1024k][256n], coalesced over n)
  {
    float s = 0.f;
    #pragma unroll 4
    for (int k = pp * 256; k < pp * 256 + 256; ++k)
      s = fmaf(hrow[k], mlp_w2[(size_t)k * 256 + n], s);
    part4[pp][n] = s;
  }
  __syncthreads();
  if (tid < 256) {
    tn[tid] = tn[tid] + mlp_b2[tid] +
              ((part4[0][tid] + part4[1][tid]) + (part4[2][tid] + part4[3][tid]));
  }
  __syncthreads();
  // head: logits + softmax (head_w [256d][1000n], coalesced over n)
  float acc = 0.f;
  if (tid < NCLS) {
    float a0 = 0, a1 = 0, a2 = 0, a3 = 0;
    #pragma unroll 2
    for (int d2 = 0; d2 < 256; d2 += 4) {
      a0 = fmaf(tn[d2 + 0], head_w[(size_t)(d2 + 0) * NCLS + tid], a0);
      a1 = fmaf(tn[d2 + 1], head_w[(size_t)(d2 + 1) * NCLS + tid], a1);
      a2 = fmaf(tn[d2 + 2], head_w[(size_t)(d2 + 2) * NCLS + tid], a2);
      a3 = fmaf(tn[d2 + 3], head_w[(size_t)(d2 + 3) * NCLS + tid], a3);
    }
    acc = head_b[tid] + ((a0 + a1) + (a2 + a3));
  }
  float mx = (tid < NCLS) ? acc : -1e30f;
  #pragma unroll
  for (int s = 1; s < 64; s <<= 1) mx = fmaxf(mx, __shfl_xor(mx, s, 64));
  __syncthreads();
  if (lane == 0) red[wid] = mx;
  __syncthreads();
  if (tid == 0) {
    float mm = red[0];
    #pragma unroll
    for (int i = 1; i < 16; ++i) mm = fmaxf(mm, red[i]);
    red[0] = mm;
  }
  __syncthreads();
  float gmax = red[0];
  float e = (tid < NCLS) ? expf(acc - gmax) : 0.f;
  float ss = e;
  #pragma unroll
  for (int s = 1; s < 64; s <<= 1) ss += __shfl_xor(ss, s, 64);
  __syncthreads();
  if (lane == 0) red[wid] = ss;
  __syncthreads();
  if (tid == 0) {
    float t2 = 0.f;
    #pragma unroll
    for (int i = 0; i < 16; ++i) t2 += red[i];
    red[0] = t2;
  }
  __syncthreads();
  if (tid < NCLS) out[(size_t)b * NCLS + tid] = e / red[0];
}

// ---------------- launch ----------------
extern "C" void kernel_launch(void* const* d_in, const int* in_sizes, int n_in,
                              void* d_out, int out_size, void* d_ws, size_t ws_size,
                              hipStream_t stream) {
  const float* x        = (const float*)d_in[0];
  const float* class_tk = (const float*)d_in[1];
  const float* pos_emb  = (const float*)d_in[2];
  const float* patch_w  = (const float*)d_in[3];
  const float* patch_b  = (const float*)d_in[4];
  const float* wq       = (const float*)d_in[5];
  const float* wk       = (const float*)d_in[6];
  const float* wv       = (const float*)d_in[7];
  const float* proj_w   = (const float*)d_in[8];
  const float* proj_b   = (const float*)d_in[9];
  const float* mlp_w1   = (const float*)d_in[10];
  const float* mlp_b1   = (const float*)d_in[11];
  const float* mlp_w2   = (const float*)d_in[12];
  const float* mlp_b2   = (const float*)d_in[13];
  const float* ln1_g    = (const float*)d_in[14];
  const float* ln1_b    = (const float*)d_in[15];
  const float* ln2_g    = (const float*)d_in[16];
  const float* ln2_b    = (const float*)d_in[17];
  const float* head_w   = (const float*)d_in[18];
  const float* head_b   = (const float*)d_in[19];
  float* out = (float*)d_out;

  float* ws = (float*)d_ws;
  const size_t NTOK = (size_t)M_ROWS * D;   // 526336
  float* t    = ws;                          // [2056][256] fp32
  u16*  xnh   = (u16*)(ws + NTOK);           // ln1 split planes
  u16*  xnl   = xnh + NTOK;
  float* kk   = ws + 2 * NTOK;               // K transposed [b][h][s]
  float* v    = ws + 3 * NTOK;               // V transposed
  float* ocls = ws + 4 * NTOK;               // [8][256]
  u16*  Wkv   = (u16*)(ws + 4 * NTOK + 4096); // kh,kl,vh,vl (4*65536 u16)

  stage0<<<1152, 256, 0, stream>>>(x, patch_w, patch_b, pos_emb, class_tk, wk, wv, Wkv, t);

  ln_split<<<(M_ROWS + 3) / 4, 256, 0, stream>>>(t, xnh, xnl, ln1_g, ln1_b, M_ROWS);

  kv_kernel<<<dim3(4, 33, 2), 256, 0, stream>>>(xnh, xnl, Wkv, kk, v);

  attn_cls<<<dim3(256, Bsz), 256, 0, stream>>>(xnh, xnl, wq, kk, v, ocls);

  tail_kernel<<<Bsz, 1024, 0, stream>>>(ocls, proj_w, proj_b, t, ln2_g, ln2_b,
                                        mlp_w1, mlp_b1, mlp_w2, mlp_b2,
                                        head_w, head_b, out);
}